// Round 2
// 1178.931 us; speedup vs baseline: 1.1179x; 1.1179x over previous
//
#include <hip/hip_runtime.h>

#define GLOBAL_AS __attribute__((address_space(1)))
#define LDS_AS    __attribute__((address_space(3)))

typedef __bf16 bf16x8 __attribute__((ext_vector_type(8)));
typedef float  floatx4 __attribute__((ext_vector_type(4)));
typedef unsigned short ushort8 __attribute__((ext_vector_type(8)));

static constexpr int M_BATCH = 4096;
static constexpr int NPTS    = 512;
static constexpr int EMB     = 2048;
static constexpr int F0      = 1023;     // 2*NPTS-1
static constexpr int F0P     = 1024;     // padded feature count, K multiple of 64
static constexpr int K0      = 9 * F0P;  // 9216
static constexpr int K12     = 9 * EMB;  // 18432

// ---- float -> bf16 round-to-nearest-even ----
__device__ __forceinline__ unsigned short f2bf(float f) {
    unsigned int u = __float_as_uint(f);
    u += 0x7fffu + ((u >> 16) & 1u);
    return (unsigned short)(u >> 16);
}

// ---- relu + 8 cubic B-spline bases, mirroring the reference recursion ----
__device__ __forceinline__ void kan_phi(float x, float* v) {
    float g[12];
    #pragma unroll
    for (int i = 0; i < 12; ++i) g[i] = (float)(i - 3) * 0.4f - 1.0f;
    float b[11];
    #pragma unroll
    for (int i = 0; i < 11; ++i) b[i] = (x >= g[i] && x < g[i + 1]) ? 1.0f : 0.0f;
    #pragma unroll
    for (int k = 1; k <= 3; ++k) {
        #pragma unroll
        for (int i = 0; i + k < 11; ++i) {
            float left  = (x - g[i]) / (g[i + k] - g[i]);
            float right = (g[i + k + 1] - x) / (g[i + k + 1] - g[i + 1]);
            b[i] = left * b[i] + right * b[i + 1];
        }
    }
    v[0] = x > 0.0f ? x : 0.0f;
    #pragma unroll
    for (int i = 0; i < 8; ++i) v[1 + i] = b[i];
}

// ---- fused aux: blocks [0, Nrows) expand activation rows; blocks
//      [Nrows, Nrows+O) pack weight rows. Both write basis-major K layout
//      [j*FP + f] matching the GEMM. (unchanged, R5-verified) ----
template<int FP, int MODE>
__global__ __launch_bounds__(256)
void aux_kernel(const float* __restrict__ p0,
                const float* __restrict__ p1,
                unsigned short* __restrict__ phi,
                int F, int Nrows,
                const float* __restrict__ bw,
                const float* __restrict__ sw,
                const float* __restrict__ sc,
                unsigned short* __restrict__ wt) {
    __shared__ __align__(16) unsigned short lds[8 * 264];
    __shared__ float scb[256];
    const int tid = threadIdx.x;

    if ((int)blockIdx.x < Nrows) {
        // ---------- expand row n ----------
        const int n = blockIdx.x;
        unsigned short* dst = phi + (size_t)n * (size_t)(9 * FP);
        for (int base = 0; base < FP; base += 256) {
            int f = base + tid;
            bool valid = f < F;
            float x;
            if (MODE == 1) {
                const float* src = (f & 1) ? p1 : p0;
                x = valid ? src[(size_t)n * NPTS + (f >> 1)] : 0.0f;
            } else {
                size_t idx = (size_t)n * F + f;
                x = valid ? (p0[idx] + p1[idx]) : 0.0f;
            }
            float v[9];
            kan_phi(x, v);
            #pragma unroll
            for (int j = 0; j < 9; ++j)
                dst[j * FP + f] = valid ? f2bf(v[j]) : (unsigned short)0;
        }
    } else {
        // ---------- pack weight row o ----------
        const int o = blockIdx.x - Nrows;
        unsigned short* dst = wt + (size_t)o * (size_t)(9 * FP);
        const float4* swr = reinterpret_cast<const float4*>(sw + (size_t)o * F * 8);
        const int F4 = 2 * F;

        for (int base = 0; base < FP; base += 256) {
            int f = base + tid;
            bool valid = f < F;
            size_t s = (size_t)o * F + f;
            dst[f] = valid ? f2bf(bw[s]) : (unsigned short)0;
            scb[tid] = valid ? sc[s] : 0.0f;
            __syncthreads();

            #pragma unroll
            for (int r = 0; r < 2; ++r) {
                int t4 = r * 256 + tid;
                int g4 = base * 2 + t4;
                float4 v = (g4 < F4) ? swr[g4] : float4{0.f, 0.f, 0.f, 0.f};
                int flat = t4 * 4;
                #pragma unroll
                for (int c = 0; c < 4; ++c) {
                    int fl = flat + c;
                    int fL = fl >> 3;
                    int j  = fl & 7;
                    float xv = (c == 0) ? v.x : (c == 1) ? v.y : (c == 2) ? v.z : v.w;
                    lds[j * 264 + fL] = f2bf(xv * scb[fL]);
                }
            }
            __syncthreads();

            {
                int j  = tid >> 5;
                int f8 = (tid & 31) * 8;
                ushort8 u = *reinterpret_cast<const ushort8*>(&lds[j * 264 + f8]);
                *reinterpret_cast<ushort8*>(dst + (size_t)(j + 1) * FP + base + f8) = u;
            }
            __syncthreads();
        }
    }
}

// ---- bf16 GEMM: 256x256 tile, BK=64, 8 waves (2M x 4N), 4-phase pipelined
//      schedule (T3+T4): per phase {ds_read subtile || 1 half-tile prefetch ->
//      s_barrier -> lgkmcnt(0) -> setprio(1) 16xMFMA setprio(0) -> s_barrier},
//      counted vmcnt(6) once per K-tile (3 half-tiles in flight, never 0 in
//      main loop). XOR-swizzled LDS via pre-swizzled global source (linear
//      global_load_lds dest). Epilogue uses clamped same-data restage so vmcnt
//      counts stay exact. Split-K via blockIdx.z into per-slice partials.
//      Region/phase safety: B0,A0 ds_read in ph1 -> overwrite issue ph2/ph3;
//      B1 read ph2 -> issue ph4; A1 read ph3 -> issue next-group ph1. Every
//      overwrite issue is >=1 full barrier pair after the region's reads
//      drained (lgkmcnt(0) precedes each phase's 2nd barrier).
#define STAGE_H(GB, LB) do { \
    __builtin_amdgcn_global_load_lds((const GLOBAL_AS void*)((GB) + (size_t)r6 * K + scol), \
        (LDS_AS void*)((LB) + wv512), 16, 0, 0); \
    __builtin_amdgcn_global_load_lds((const GLOBAL_AS void*)((GB) + (size_t)(64 + r6) * K + scol), \
        (LDS_AS void*)((LB) + 4096 + wv512), 16, 0, 0); \
} while (0)

__global__ __launch_bounds__(512, 2)
void gemm_bt_256(const unsigned short* __restrict__ A,
                 const unsigned short* __restrict__ B,
                 float* __restrict__ C,
                 int M, int N, int K, int kchunk) {
    __shared__ __align__(16) unsigned short Alds[2 * 16384];  // 2 bufs x 256x64
    __shared__ __align__(16) unsigned short Blds[2 * 16384];

    const int tid  = threadIdx.x;
    const int wv   = tid >> 6;
    const int lane = tid & 63;
    const int fr   = lane & 15;
    const int fq   = lane >> 4;
    const int wmi  = wv >> 2;    // 0..1  (M wave)
    const int wni  = wv & 3;     // 0..3  (N wave)

    const int bm = blockIdx.y;
    const int bn = blockIdx.x;
    const int kbase = blockIdx.z * kchunk;
    const int NT = kchunk >> 6;
    float* Cz = C + (size_t)blockIdx.z * (size_t)M * N;

    // staging geometry: thread t covers row r6, col-slot p=t&7; source col
    // pre-swizzled so linear LDS dest + swizzled ds_read agree (rule #21)
    const int r6    = tid >> 3;                        // 0..63
    const int scol  = ((tid & 7) ^ (r6 & 7)) * 8;      // k-elem offset
    const int wv512 = wv * 512;                        // lds elems per wave

    const unsigned short* Ab = A + (size_t)bm * 256 * K;
    const unsigned short* Bb = B + (size_t)bn * 256 * K;

    // ds_read fragment offsets (elems); row&7 == fr&7 for all frags
    const int aoff0 = (wmi * 16 + fr) * 64 + ((fq    ) ^ (fr & 7)) * 8;
    const int aoff1 = (wmi * 16 + fr) * 64 + ((4 + fq) ^ (fr & 7)) * 8;
    const int boff0 = (wni * 16 + fr) * 64 + ((fq    ) ^ (fr & 7)) * 8;
    const int boff1 = (wni * 16 + fr) * 64 + ((4 + fq) ^ (fr & 7)) * 8;

    floatx4 zero = {0.f, 0.f, 0.f, 0.f};
    floatx4 acc[8][4];
    #pragma unroll
    for (int i = 0; i < 8; ++i)
        #pragma unroll
        for (int j = 0; j < 4; ++j)
            acc[i][j] = zero;

    // ---- prologue: tile0 (B0,A0,B1,A1) + tile1 (B0,A0,B1) = 14 loads ----
    {
        const unsigned short* Ag = Ab + kbase;
        const unsigned short* Bg = Bb + kbase;
        STAGE_H(Bg,                   Blds);                 // B0 t0
        STAGE_H(Ag,                   Alds);                 // A0 t0
        STAGE_H(Bg + (size_t)128 * K, Blds + 8192);          // B1 t0
        STAGE_H(Ag + (size_t)128 * K, Alds + 8192);          // A1 t0
        STAGE_H(Bg + 64,                   Blds + 16384);         // B0 t1
        STAGE_H(Ag + 64,                   Alds + 16384);         // A0 t1
        STAGE_H(Bg + (size_t)128 * K + 64, Blds + 16384 + 8192);  // B1 t1
    }
    asm volatile("s_waitcnt vmcnt(6)" ::: "memory");   // tile0 landed
    __builtin_amdgcn_s_barrier();

    for (int t = 0; t < NT; ++t) {
        unsigned short* Ac = Alds + (t & 1) * 16384;
        unsigned short* Bc = Blds + (t & 1) * 16384;
        const int t1 = (t + 1 < NT) ? t + 1 : NT - 1;   // clamp: same-data restage
        const int t2 = (t + 2 < NT) ? t + 2 : NT - 1;
        const unsigned short* Ag1 = Ab + kbase + t1 * 64;
        const unsigned short* Ag2 = Ab + kbase + t2 * 64;
        const unsigned short* Bg2 = Bb + kbase + t2 * 64;
        unsigned short* Al1 = Alds + (t1 & 1) * 16384;
        unsigned short* Al2 = Alds + (t2 & 1) * 16384;
        unsigned short* Bl2 = Blds + (t2 & 1) * 16384;

        bf16x8 a_lo[4][2], a_hi[4][2], b_lo[2][2], b_hi[2][2];

        // ---------- phase 1: read A0+B0, stage A1(t1), MFMA mt0-3 x nt0-1 ----
        #pragma unroll
        for (int mt = 0; mt < 4; ++mt) {
            a_lo[mt][0] = *reinterpret_cast<const bf16x8*>(Ac + mt * 2048 + aoff0);
            a_lo[mt][1] = *reinterpret_cast<const bf16x8*>(Ac + mt * 2048 + aoff1);
        }
        #pragma unroll
        for (int nt = 0; nt < 2; ++nt) {
            b_lo[nt][0] = *reinterpret_cast<const bf16x8*>(Bc + nt * 4096 + boff0);
            b_lo[nt][1] = *reinterpret_cast<const bf16x8*>(Bc + nt * 4096 + boff1);
        }
        STAGE_H(Ag1 + (size_t)128 * K, Al1 + 8192);          // A1(t+1)
        __builtin_amdgcn_s_barrier();
        asm volatile("s_waitcnt lgkmcnt(0)" ::: "memory");
        __builtin_amdgcn_s_setprio(1);
        #pragma unroll
        for (int mt = 0; mt < 4; ++mt)
            #pragma unroll
            for (int nt = 0; nt < 2; ++nt) {
                acc[mt][nt] = __builtin_amdgcn_mfma_f32_16x16x32_bf16(a_lo[mt][0], b_lo[nt][0], acc[mt][nt], 0, 0, 0);
                acc[mt][nt] = __builtin_amdgcn_mfma_f32_16x16x32_bf16(a_lo[mt][1], b_lo[nt][1], acc[mt][nt], 0, 0, 0);
            }
        __builtin_amdgcn_s_setprio(0);
        __builtin_amdgcn_s_barrier();

        // ---------- phase 2: read B1, stage B0(t2), MFMA mt0-3 x nt2-3 ----
        #pragma unroll
        for (int nt = 0; nt < 2; ++nt) {
            b_hi[nt][0] = *reinterpret_cast<const bf16x8*>(Bc + (2 + nt) * 4096 + boff0);
            b_hi[nt][1] = *reinterpret_cast<const bf16x8*>(Bc + (2 + nt) * 4096 + boff1);
        }
        STAGE_H(Bg2, Bl2);                                   // B0(t+2)
        __builtin_amdgcn_s_barrier();
        asm volatile("s_waitcnt lgkmcnt(0)" ::: "memory");
        __builtin_amdgcn_s_setprio(1);
        #pragma unroll
        for (int mt = 0; mt < 4; ++mt)
            #pragma unroll
            for (int nt = 0; nt < 2; ++nt) {
                acc[mt][2 + nt] = __builtin_amdgcn_mfma_f32_16x16x32_bf16(a_lo[mt][0], b_hi[nt][0], acc[mt][2 + nt], 0, 0, 0);
                acc[mt][2 + nt] = __builtin_amdgcn_mfma_f32_16x16x32_bf16(a_lo[mt][1], b_hi[nt][1], acc[mt][2 + nt], 0, 0, 0);
            }
        __builtin_amdgcn_s_setprio(0);
        __builtin_amdgcn_s_barrier();

        // ---------- phase 3: read A1, stage A0(t2), MFMA mt4-7 x nt0-1 ----
        #pragma unroll
        for (int mt = 0; mt < 4; ++mt) {
            a_hi[mt][0] = *reinterpret_cast<const bf16x8*>(Ac + (4 + mt) * 2048 + aoff0);
            a_hi[mt][1] = *reinterpret_cast<const bf16x8*>(Ac + (4 + mt) * 2048 + aoff1);
        }
        STAGE_H(Ag2, Al2);                                   // A0(t+2)
        __builtin_amdgcn_s_barrier();
        asm volatile("s_waitcnt lgkmcnt(0)" ::: "memory");
        __builtin_amdgcn_s_setprio(1);
        #pragma unroll
        for (int mt = 0; mt < 4; ++mt)
            #pragma unroll
            for (int nt = 0; nt < 2; ++nt) {
                acc[4 + mt][nt] = __builtin_amdgcn_mfma_f32_16x16x32_bf16(a_hi[mt][0], b_lo[nt][0], acc[4 + mt][nt], 0, 0, 0);
                acc[4 + mt][nt] = __builtin_amdgcn_mfma_f32_16x16x32_bf16(a_hi[mt][1], b_lo[nt][1], acc[4 + mt][nt], 0, 0, 0);
            }
        __builtin_amdgcn_s_setprio(0);
        __builtin_amdgcn_s_barrier();

        // ---------- phase 4: stage B1(t2), MFMA mt4-7 x nt2-3, vmcnt(6) ----
        STAGE_H(Bg2 + (size_t)128 * K, Bl2 + 8192);          // B1(t+2)
        __builtin_amdgcn_s_barrier();
        __builtin_amdgcn_s_setprio(1);
        #pragma unroll
        for (int mt = 0; mt < 4; ++mt)
            #pragma unroll
            for (int nt = 0; nt < 2; ++nt) {
                acc[4 + mt][2 + nt] = __builtin_amdgcn_mfma_f32_16x16x32_bf16(a_hi[mt][0], b_hi[nt][0], acc[4 + mt][2 + nt], 0, 0, 0);
                acc[4 + mt][2 + nt] = __builtin_amdgcn_mfma_f32_16x16x32_bf16(a_hi[mt][1], b_hi[nt][1], acc[4 + mt][2 + nt], 0, 0, 0);
            }
        __builtin_amdgcn_s_setprio(0);
        // tile t+1 fully landed; B0/A0/B1 of t+2 (6 loads) stay in flight
        asm volatile("s_waitcnt vmcnt(6)" ::: "memory");
        __builtin_amdgcn_s_barrier();
    }

    // ---- epilogue: C layout col=fr, row=fq*4+r (verified mapping) ----
    #pragma unroll
    for (int mt = 0; mt < 8; ++mt) {
        #pragma unroll
        for (int nt = 0; nt < 4; ++nt) {
            #pragma unroll
            for (int r = 0; r < 4; ++r) {
                int gr = bm * 256 + mt * 32 + wmi * 16 + fq * 4 + r;
                int gc = bn * 256 + nt * 64 + wni * 16 + fr;
                Cz[(size_t)gr * N + gc] = acc[mt][nt][r];
            }
        }
    }
}

// ---- layer-2 fixup: out = sum of 8 k-slice partials ----
__global__ void add8_kernel(const float* __restrict__ p,
                            float* __restrict__ out, int n4, int slice4) {
    int i = blockIdx.x * blockDim.x + threadIdx.x;
    if (i >= n4) return;
    const float4* p4 = reinterpret_cast<const float4*>(p);
    float4 s = p4[i];
    #pragma unroll
    for (int z = 1; z < 8; ++z) {
        float4 v = p4[(size_t)z * slice4 + i];
        s.x += v.x; s.y += v.y; s.z += v.z; s.w += v.w;
    }
    reinterpret_cast<float4*>(out)[i] = s;
}

extern "C" void kernel_launch(void* const* d_in, const int* in_sizes, int n_in,
                              void* d_out, int out_size, void* d_ws, size_t ws_size,
                              hipStream_t stream) {
    const float* xs  = (const float*)d_in[0];
    const float* ys  = (const float*)d_in[1];
    const float* bw0 = (const float*)d_in[2];
    const float* sw0 = (const float*)d_in[3];
    const float* sc0 = (const float*)d_in[4];
    const float* bw1 = (const float*)d_in[5];
    const float* sw1 = (const float*)d_in[6];
    const float* sc1 = (const float*)d_in[7];
    const float* bw2 = (const float*)d_in[8];
    const float* sw2 = (const float*)d_in[9];
    const float* sc2 = (const float*)d_in[10];

    // workspace: Phi 151.0M | Wt 75.5M | Cpart 67.1M (reused per layer)
    char* ws = (char*)d_ws;
    unsigned short* Phi = (unsigned short*)ws;
    unsigned short* Wt  = (unsigned short*)(ws + 150994944);
    float* Cpart = (float*)(ws + 150994944 + 75497472);
    float* out = (float*)d_out;
    (void)ws_size; (void)in_sizes; (void)n_in; (void)out_size;

    const int T = 256;
    const size_t MN = (size_t)M_BATCH * EMB;

    // ---- layer 0: 4096 x 9216 x 2048, split-K=2 -> 256 blocks (1/CU) ----
    aux_kernel<F0P, 1><<<M_BATCH + EMB, T, 0, stream>>>(
        xs, ys, Phi, F0, M_BATCH, bw0, sw0, sc0, Wt);
    gemm_bt_256<<<dim3(8, 16, 2), 512, 0, stream>>>(Phi, Wt, Cpart, M_BATCH, EMB, K0, K0 / 2);

    // ---- layer 1: expand fuses p0+p1 partial reduction ----
    aux_kernel<EMB, 0><<<M_BATCH + EMB, T, 0, stream>>>(
        Cpart, Cpart + MN, Phi, EMB, M_BATCH, bw1, sw1, sc1, Wt);
    gemm_bt_256<<<dim3(8, 16, 2), 512, 0, stream>>>(Phi, Wt, Cpart, M_BATCH, EMB, K12, K12 / 2);

    // ---- layer 2: 4096 x 18432 x 512, split-K=8 -> 256 blocks, 36 iters ----
    aux_kernel<EMB, 0><<<M_BATCH + NPTS, T, 0, stream>>>(
        Cpart, Cpart + MN, Phi, EMB, M_BATCH, bw2, sw2, sc2, Wt);
    gemm_bt_256<<<dim3(2, 16, 8), 512, 0, stream>>>(Phi, Wt, Cpart, M_BATCH, NPTS, K12, K12 / 8);
    add8_kernel<<<(M_BATCH * NPTS / 4 + T - 1) / T, T, 0, stream>>>(
        Cpart, out, M_BATCH * NPTS / 4, M_BATCH * NPTS / 4);
}

// Round 3
// 998.928 us; speedup vs baseline: 1.3194x; 1.1802x over previous
//
#include <hip/hip_runtime.h>

#define GLOBAL_AS __attribute__((address_space(1)))
#define LDS_AS    __attribute__((address_space(3)))

typedef __bf16 bf16x8 __attribute__((ext_vector_type(8)));
typedef float  floatx4 __attribute__((ext_vector_type(4)));
typedef unsigned short ushort8 __attribute__((ext_vector_type(8)));

static constexpr int M_BATCH = 4096;
static constexpr int NPTS    = 512;
static constexpr int EMB     = 2048;
static constexpr int F0      = 1023;     // 2*NPTS-1
static constexpr int F0P     = 1024;     // padded feature count, K multiple of 64
static constexpr int K0      = 9 * F0P;  // 9216
static constexpr int K12     = 9 * EMB;  // 18432

// ---- float -> bf16 round-to-nearest-even ----
__device__ __forceinline__ unsigned short f2bf(float f) {
    unsigned int u = __float_as_uint(f);
    u += 0x7fffu + ((u >> 16) & 1u);
    return (unsigned short)(u >> 16);
}

// ---- relu + 8 cubic B-spline bases, mirroring the reference recursion.
//      All grid values are compile-time constants, so the divides fold to
//      constant reciprocal multiplies (0 runtime v_div sequences). ----
__device__ __forceinline__ void kan_phi(float x, float* v) {
    float b[11];
    #pragma unroll
    for (int i = 0; i < 11; ++i) {
        const float gl = (float)(i - 3) * 0.4f - 1.0f;
        const float gr = (float)(i - 2) * 0.4f - 1.0f;
        b[i] = (x >= gl && x < gr) ? 1.0f : 0.0f;
    }
    #pragma unroll
    for (int k = 1; k <= 3; ++k) {
        #pragma unroll
        for (int i = 0; i + k < 11; ++i) {
            const float gi   = (float)(i - 3) * 0.4f - 1.0f;
            const float gi1  = (float)(i - 2) * 0.4f - 1.0f;
            const float gik  = (float)(i + k - 3) * 0.4f - 1.0f;
            const float gik1 = (float)(i + k - 2) * 0.4f - 1.0f;
            const float invL = 1.0f / (gik - gi);    // constant-folded
            const float invR = 1.0f / (gik1 - gi1);  // constant-folded
            b[i] = (x - gi) * invL * b[i] + (gik1 - x) * invR * b[i + 1];
        }
    }
    v[0] = x > 0.0f ? x : 0.0f;
    #pragma unroll
    for (int i = 0; i < 8; ++i) v[1 + i] = b[i];
}

// ---- fused aux (f-major K layout: k = f*9 + s, s=0 base / 1..8 splines).
//      Blocks [0,NE): expand activation rows; blocks [NE,..): pack weight
//      rows. Each thread owns 8 consecutive features -> its 9-slot x 8-feat
//      output is a contiguous 144 B run (16B-aligned) written as 9 ushort8
//      stores. No LDS, no syncthreads, no divides. ----
template<int FP, int MODE>
__global__ __launch_bounds__(256)
void aux2_kernel(const float* __restrict__ p0,
                 const float* __restrict__ p1,
                 unsigned short* __restrict__ phi,
                 int F, int NE,
                 const float* __restrict__ bw,
                 const float* __restrict__ sw,
                 const float* __restrict__ sc,
                 unsigned short* __restrict__ wt) {
    constexpr int RPB = (FP == 1024) ? 2 : 1;    // rows per block
    const int tid = threadIdx.x;
    const int u   = (RPB == 2) ? (tid & 127) : tid;   // 8-feature unit index
    const int f0  = u * 8;

    if ((int)blockIdx.x < NE) {
        // ---------- expand row n ----------
        const int n = blockIdx.x * RPB + (RPB == 2 ? (tid >> 7) : 0);
        float xv[8];
        if (MODE == 1) {
            // f = f0+i: even -> xs[n][f>>1], odd -> ys[n][f>>1]
            const float4 xsv = *reinterpret_cast<const float4*>(p0 + (size_t)n * NPTS + (f0 >> 1));
            const float4 ysv = *reinterpret_cast<const float4*>(p1 + (size_t)n * NPTS + (f0 >> 1));
            xv[0] = xsv.x; xv[1] = ysv.x; xv[2] = xsv.y; xv[3] = ysv.y;
            xv[4] = xsv.z; xv[5] = ysv.z; xv[6] = xsv.w; xv[7] = ysv.w;
        } else {
            const float4 a0 = *reinterpret_cast<const float4*>(p0 + (size_t)n * F + f0);
            const float4 a1 = *reinterpret_cast<const float4*>(p0 + (size_t)n * F + f0 + 4);
            const float4 c0 = *reinterpret_cast<const float4*>(p1 + (size_t)n * F + f0);
            const float4 c1 = *reinterpret_cast<const float4*>(p1 + (size_t)n * F + f0 + 4);
            xv[0] = a0.x + c0.x; xv[1] = a0.y + c0.y; xv[2] = a0.z + c0.z; xv[3] = a0.w + c0.w;
            xv[4] = a1.x + c1.x; xv[5] = a1.y + c1.y; xv[6] = a1.z + c1.z; xv[7] = a1.w + c1.w;
        }
        ushort8 out[9];
        #pragma unroll
        for (int i = 0; i < 8; ++i) {
            float v[9];
            kan_phi(xv[i], v);
            const bool valid = (f0 + i) < F;
            #pragma unroll
            for (int s = 0; s < 9; ++s) {
                const int flat = i * 9 + s;
                out[flat >> 3][flat & 7] = valid ? f2bf(v[s]) : (unsigned short)0;
            }
        }
        ushort8* dst = reinterpret_cast<ushort8*>(phi + (size_t)n * (size_t)(9 * FP) + (size_t)f0 * 9);
        #pragma unroll
        for (int w = 0; w < 9; ++w) dst[w] = out[w];
    } else {
        // ---------- pack weight row o ----------
        const int o = (blockIdx.x - NE) * RPB + (RPB == 2 ? (tid >> 7) : 0);
        const float4* swr = reinterpret_cast<const float4*>(sw + ((size_t)o * F + f0) * 8);
        float scv[8], bwv[8];
        #pragma unroll
        for (int i = 0; i < 8; ++i) {
            const bool valid = (f0 + i) < F;
            scv[i] = valid ? sc[(size_t)o * F + f0 + i] : 0.0f;
            bwv[i] = valid ? bw[(size_t)o * F + f0 + i] : 0.0f;
        }
        ushort8 out[9];
        #pragma unroll
        for (int i = 0; i < 8; ++i) {
            const bool valid = (f0 + i) < F;
            float4 lo = float4{0.f, 0.f, 0.f, 0.f}, hi = float4{0.f, 0.f, 0.f, 0.f};
            if (valid) { lo = swr[i * 2]; hi = swr[i * 2 + 1]; }
            const float s = scv[i];
            float w9[9];
            w9[0] = bwv[i];
            w9[1] = lo.x * s; w9[2] = lo.y * s; w9[3] = lo.z * s; w9[4] = lo.w * s;
            w9[5] = hi.x * s; w9[6] = hi.y * s; w9[7] = hi.z * s; w9[8] = hi.w * s;
            #pragma unroll
            for (int s2 = 0; s2 < 9; ++s2) {
                const int flat = i * 9 + s2;
                out[flat >> 3][flat & 7] = valid ? f2bf(w9[s2]) : (unsigned short)0;
            }
        }
        ushort8* dst = reinterpret_cast<ushort8*>(wt + (size_t)o * (size_t)(9 * FP) + (size_t)f0 * 9);
        #pragma unroll
        for (int w = 0; w < 9; ++w) dst[w] = out[w];
    }
}

// ---- bf16 GEMM: 256x256 tile, BK=64, 8 waves (2M x 4N), 4-phase pipelined
//      schedule (T3+T4): per phase {ds_read subtile || 1 half-tile prefetch ->
//      s_barrier -> lgkmcnt(0) -> setprio(1) 16xMFMA setprio(0) -> s_barrier},
//      counted vmcnt(6) once per K-tile (3 half-tiles in flight, never 0 in
//      main loop). XOR-swizzled LDS via pre-swizzled global source (linear
//      global_load_lds dest). Epilogue uses clamped same-data restage so vmcnt
//      counts stay exact. Split-K via blockIdx.z into per-slice partials.
//      (R2-verified: 288 us @ L1, MfmaUtil 46, 0 bank conflicts.) ----
#define STAGE_H(GB, LB) do { \
    __builtin_amdgcn_global_load_lds((const GLOBAL_AS void*)((GB) + (size_t)r6 * K + scol), \
        (LDS_AS void*)((LB) + wv512), 16, 0, 0); \
    __builtin_amdgcn_global_load_lds((const GLOBAL_AS void*)((GB) + (size_t)(64 + r6) * K + scol), \
        (LDS_AS void*)((LB) + 4096 + wv512), 16, 0, 0); \
} while (0)

__global__ __launch_bounds__(512, 2)
void gemm_bt_256(const unsigned short* __restrict__ A,
                 const unsigned short* __restrict__ B,
                 float* __restrict__ C,
                 int M, int N, int K, int kchunk) {
    __shared__ __align__(16) unsigned short Alds[2 * 16384];  // 2 bufs x 256x64
    __shared__ __align__(16) unsigned short Blds[2 * 16384];

    const int tid  = threadIdx.x;
    const int wv   = tid >> 6;
    const int lane = tid & 63;
    const int fr   = lane & 15;
    const int fq   = lane >> 4;
    const int wmi  = wv >> 2;    // 0..1  (M wave)
    const int wni  = wv & 3;     // 0..3  (N wave)

    const int bm = blockIdx.y;
    const int bn = blockIdx.x;
    const int kbase = blockIdx.z * kchunk;
    const int NT = kchunk >> 6;
    float* Cz = C + (size_t)blockIdx.z * (size_t)M * N;

    // staging geometry: thread t covers row r6, col-slot p=t&7; source col
    // pre-swizzled so linear LDS dest + swizzled ds_read agree (rule #21)
    const int r6    = tid >> 3;                        // 0..63
    const int scol  = ((tid & 7) ^ (r6 & 7)) * 8;      // k-elem offset
    const int wv512 = wv * 512;                        // lds elems per wave

    const unsigned short* Ab = A + (size_t)bm * 256 * K;
    const unsigned short* Bb = B + (size_t)bn * 256 * K;

    // ds_read fragment offsets (elems); row&7 == fr&7 for all frags
    const int aoff0 = (wmi * 16 + fr) * 64 + ((fq    ) ^ (fr & 7)) * 8;
    const int aoff1 = (wmi * 16 + fr) * 64 + ((4 + fq) ^ (fr & 7)) * 8;
    const int boff0 = (wni * 16 + fr) * 64 + ((fq    ) ^ (fr & 7)) * 8;
    const int boff1 = (wni * 16 + fr) * 64 + ((4 + fq) ^ (fr & 7)) * 8;

    floatx4 zero = {0.f, 0.f, 0.f, 0.f};
    floatx4 acc[8][4];
    #pragma unroll
    for (int i = 0; i < 8; ++i)
        #pragma unroll
        for (int j = 0; j < 4; ++j)
            acc[i][j] = zero;

    // ---- prologue: tile0 (B0,A0,B1,A1) + tile1 (B0,A0,B1) = 14 loads ----
    {
        const unsigned short* Ag = Ab + kbase;
        const unsigned short* Bg = Bb + kbase;
        STAGE_H(Bg,                   Blds);                 // B0 t0
        STAGE_H(Ag,                   Alds);                 // A0 t0
        STAGE_H(Bg + (size_t)128 * K, Blds + 8192);          // B1 t0
        STAGE_H(Ag + (size_t)128 * K, Alds + 8192);          // A1 t0
        STAGE_H(Bg + 64,                   Blds + 16384);         // B0 t1
        STAGE_H(Ag + 64,                   Alds + 16384);         // A0 t1
        STAGE_H(Bg + (size_t)128 * K + 64, Blds + 16384 + 8192);  // B1 t1
    }
    asm volatile("s_waitcnt vmcnt(6)" ::: "memory");   // tile0 landed
    __builtin_amdgcn_s_barrier();

    for (int t = 0; t < NT; ++t) {
        unsigned short* Ac = Alds + (t & 1) * 16384;
        unsigned short* Bc = Blds + (t & 1) * 16384;
        const int t1 = (t + 1 < NT) ? t + 1 : NT - 1;   // clamp: same-data restage
        const int t2 = (t + 2 < NT) ? t + 2 : NT - 1;
        const unsigned short* Ag1 = Ab + kbase + t1 * 64;
        const unsigned short* Ag2 = Ab + kbase + t2 * 64;
        const unsigned short* Bg2 = Bb + kbase + t2 * 64;
        unsigned short* Al1 = Alds + (t1 & 1) * 16384;
        unsigned short* Al2 = Alds + (t2 & 1) * 16384;
        unsigned short* Bl2 = Blds + (t2 & 1) * 16384;

        bf16x8 a_lo[4][2], a_hi[4][2], b_lo[2][2], b_hi[2][2];

        // ---------- phase 1: read A0+B0, stage A1(t1), MFMA mt0-3 x nt0-1 ----
        #pragma unroll
        for (int mt = 0; mt < 4; ++mt) {
            a_lo[mt][0] = *reinterpret_cast<const bf16x8*>(Ac + mt * 2048 + aoff0);
            a_lo[mt][1] = *reinterpret_cast<const bf16x8*>(Ac + mt * 2048 + aoff1);
        }
        #pragma unroll
        for (int nt = 0; nt < 2; ++nt) {
            b_lo[nt][0] = *reinterpret_cast<const bf16x8*>(Bc + nt * 4096 + boff0);
            b_lo[nt][1] = *reinterpret_cast<const bf16x8*>(Bc + nt * 4096 + boff1);
        }
        STAGE_H(Ag1 + (size_t)128 * K, Al1 + 8192);          // A1(t+1)
        __builtin_amdgcn_s_barrier();
        asm volatile("s_waitcnt lgkmcnt(0)" ::: "memory");
        __builtin_amdgcn_s_setprio(1);
        #pragma unroll
        for (int mt = 0; mt < 4; ++mt)
            #pragma unroll
            for (int nt = 0; nt < 2; ++nt) {
                acc[mt][nt] = __builtin_amdgcn_mfma_f32_16x16x32_bf16(a_lo[mt][0], b_lo[nt][0], acc[mt][nt], 0, 0, 0);
                acc[mt][nt] = __builtin_amdgcn_mfma_f32_16x16x32_bf16(a_lo[mt][1], b_lo[nt][1], acc[mt][nt], 0, 0, 0);
            }
        __builtin_amdgcn_s_setprio(0);
        __builtin_amdgcn_s_barrier();

        // ---------- phase 2: read B1, stage B0(t2), MFMA mt0-3 x nt2-3 ----
        #pragma unroll
        for (int nt = 0; nt < 2; ++nt) {
            b_hi[nt][0] = *reinterpret_cast<const bf16x8*>(Bc + (2 + nt) * 4096 + boff0);
            b_hi[nt][1] = *reinterpret_cast<const bf16x8*>(Bc + (2 + nt) * 4096 + boff1);
        }
        STAGE_H(Bg2, Bl2);                                   // B0(t+2)
        __builtin_amdgcn_s_barrier();
        asm volatile("s_waitcnt lgkmcnt(0)" ::: "memory");
        __builtin_amdgcn_s_setprio(1);
        #pragma unroll
        for (int mt = 0; mt < 4; ++mt)
            #pragma unroll
            for (int nt = 0; nt < 2; ++nt) {
                acc[mt][2 + nt] = __builtin_amdgcn_mfma_f32_16x16x32_bf16(a_lo[mt][0], b_hi[nt][0], acc[mt][2 + nt], 0, 0, 0);
                acc[mt][2 + nt] = __builtin_amdgcn_mfma_f32_16x16x32_bf16(a_lo[mt][1], b_hi[nt][1], acc[mt][2 + nt], 0, 0, 0);
            }
        __builtin_amdgcn_s_setprio(0);
        __builtin_amdgcn_s_barrier();

        // ---------- phase 3: read A1, stage A0(t2), MFMA mt4-7 x nt0-1 ----
        #pragma unroll
        for (int mt = 0; mt < 4; ++mt) {
            a_hi[mt][0] = *reinterpret_cast<const bf16x8*>(Ac + (4 + mt) * 2048 + aoff0);
            a_hi[mt][1] = *reinterpret_cast<const bf16x8*>(Ac + (4 + mt) * 2048 + aoff1);
        }
        STAGE_H(Ag2, Al2);                                   // A0(t+2)
        __builtin_amdgcn_s_barrier();
        asm volatile("s_waitcnt lgkmcnt(0)" ::: "memory");
        __builtin_amdgcn_s_setprio(1);
        #pragma unroll
        for (int mt = 0; mt < 4; ++mt)
            #pragma unroll
            for (int nt = 0; nt < 2; ++nt) {
                acc[4 + mt][nt] = __builtin_amdgcn_mfma_f32_16x16x32_bf16(a_hi[mt][0], b_lo[nt][0], acc[4 + mt][nt], 0, 0, 0);
                acc[4 + mt][nt] = __builtin_amdgcn_mfma_f32_16x16x32_bf16(a_hi[mt][1], b_lo[nt][1], acc[4 + mt][nt], 0, 0, 0);
            }
        __builtin_amdgcn_s_setprio(0);
        __builtin_amdgcn_s_barrier();

        // ---------- phase 4: stage B1(t2), MFMA mt4-7 x nt2-3, vmcnt(6) ----
        STAGE_H(Bg2 + (size_t)128 * K, Bl2 + 8192);          // B1(t+2)
        __builtin_amdgcn_s_barrier();
        __builtin_amdgcn_s_setprio(1);
        #pragma unroll
        for (int mt = 0; mt < 4; ++mt)
            #pragma unroll
            for (int nt = 0; nt < 2; ++nt) {
                acc[4 + mt][2 + nt] = __builtin_amdgcn_mfma_f32_16x16x32_bf16(a_hi[mt][0], b_hi[nt][0], acc[4 + mt][2 + nt], 0, 0, 0);
                acc[4 + mt][2 + nt] = __builtin_amdgcn_mfma_f32_16x16x32_bf16(a_hi[mt][1], b_hi[nt][1], acc[4 + mt][2 + nt], 0, 0, 0);
            }
        __builtin_amdgcn_s_setprio(0);
        // tile t+1 fully landed; B0/A0/B1 of t+2 (6 loads) stay in flight
        asm volatile("s_waitcnt vmcnt(6)" ::: "memory");
        __builtin_amdgcn_s_barrier();
    }

    // ---- epilogue: C layout col=fr, row=fq*4+r (verified mapping) ----
    #pragma unroll
    for (int mt = 0; mt < 8; ++mt) {
        #pragma unroll
        for (int nt = 0; nt < 4; ++nt) {
            #pragma unroll
            for (int r = 0; r < 4; ++r) {
                int gr = bm * 256 + mt * 32 + wmi * 16 + fq * 4 + r;
                int gc = bn * 256 + nt * 64 + wni * 16 + fr;
                Cz[(size_t)gr * N + gc] = acc[mt][nt][r];
            }
        }
    }
}

// ---- layer-2 fixup: out = sum of 8 k-slice partials ----
__global__ void add8_kernel(const float* __restrict__ p,
                            float* __restrict__ out, int n4, int slice4) {
    int i = blockIdx.x * blockDim.x + threadIdx.x;
    if (i >= n4) return;
    const float4* p4 = reinterpret_cast<const float4*>(p);
    float4 s = p4[i];
    #pragma unroll
    for (int z = 1; z < 8; ++z) {
        float4 v = p4[(size_t)z * slice4 + i];
        s.x += v.x; s.y += v.y; s.z += v.z; s.w += v.w;
    }
    reinterpret_cast<float4*>(out)[i] = s;
}

extern "C" void kernel_launch(void* const* d_in, const int* in_sizes, int n_in,
                              void* d_out, int out_size, void* d_ws, size_t ws_size,
                              hipStream_t stream) {
    const float* xs  = (const float*)d_in[0];
    const float* ys  = (const float*)d_in[1];
    const float* bw0 = (const float*)d_in[2];
    const float* sw0 = (const float*)d_in[3];
    const float* sc0 = (const float*)d_in[4];
    const float* bw1 = (const float*)d_in[5];
    const float* sw1 = (const float*)d_in[6];
    const float* sc1 = (const float*)d_in[7];
    const float* bw2 = (const float*)d_in[8];
    const float* sw2 = (const float*)d_in[9];
    const float* sc2 = (const float*)d_in[10];

    // workspace: Phi 151.0M | Wt 75.5M | Cpart 67.1M (reused per layer)
    char* ws = (char*)d_ws;
    unsigned short* Phi = (unsigned short*)ws;
    unsigned short* Wt  = (unsigned short*)(ws + 150994944);
    float* Cpart = (float*)(ws + 150994944 + 75497472);
    float* out = (float*)d_out;
    (void)ws_size; (void)in_sizes; (void)n_in; (void)out_size;

    const int T = 256;
    const size_t MN = (size_t)M_BATCH * EMB;

    // ---- layer 0: 4096 x 9216 x 2048, split-K=2 -> 256 blocks (1/CU) ----
    // FP=1024 -> 2 rows/block: 2048 expand-blocks + 1024 pack-blocks
    aux2_kernel<F0P, 1><<<2048 + 1024, T, 0, stream>>>(
        xs, ys, Phi, F0, 2048, bw0, sw0, sc0, Wt);
    gemm_bt_256<<<dim3(8, 16, 2), 512, 0, stream>>>(Phi, Wt, Cpart, M_BATCH, EMB, K0, K0 / 2);

    // ---- layer 1: expand fuses p0+p1 partial reduction ----
    aux2_kernel<EMB, 0><<<M_BATCH + EMB, T, 0, stream>>>(
        Cpart, Cpart + MN, Phi, EMB, M_BATCH, bw1, sw1, sc1, Wt);
    gemm_bt_256<<<dim3(8, 16, 2), 512, 0, stream>>>(Phi, Wt, Cpart, M_BATCH, EMB, K12, K12 / 2);

    // ---- layer 2: 4096 x 18432 x 512, split-K=8 -> 256 blocks, 36 iters ----
    aux2_kernel<EMB, 0><<<M_BATCH + NPTS, T, 0, stream>>>(
        Cpart, Cpart + MN, Phi, EMB, M_BATCH, bw2, sw2, sc2, Wt);
    gemm_bt_256<<<dim3(2, 16, 8), 512, 0, stream>>>(Phi, Wt, Cpart, M_BATCH, NPTS, K12, K12 / 8);
    add8_kernel<<<(M_BATCH * NPTS / 4 + T - 1) / T, T, 0, stream>>>(
        Cpart, out, M_BATCH * NPTS / 4, M_BATCH * NPTS / 4);
}

// Round 5
// 920.534 us; speedup vs baseline: 1.4317x; 1.0852x over previous
//
#include <hip/hip_runtime.h>

#define GLOBAL_AS __attribute__((address_space(1)))
#define LDS_AS    __attribute__((address_space(3)))

typedef __bf16 bf16x8 __attribute__((ext_vector_type(8)));
typedef float  floatx4 __attribute__((ext_vector_type(4)));
typedef unsigned short ushort8 __attribute__((ext_vector_type(8)));

static constexpr int M_BATCH = 4096;
static constexpr int NPTS    = 512;
static constexpr int EMB     = 2048;
static constexpr int F0      = 1023;     // 2*NPTS-1
static constexpr int F0P     = 1024;     // padded feature count, K multiple of 64
static constexpr int K0      = 9 * F0P;  // 9216
static constexpr int K12     = 9 * EMB;  // 18432

// ---- float -> bf16 round-to-nearest-even ----
__device__ __forceinline__ unsigned short f2bf(float f) {
    unsigned int u = __float_as_uint(f);
    u += 0x7fffu + ((u >> 16) & 1u);
    return (unsigned short)(u >> 16);
}

// ---- relu + 8 cubic B-spline bases, mirroring the reference recursion.
//      All grid values are compile-time constants, so the divides fold to
//      constant reciprocal multiplies (0 runtime v_div sequences). ----
__device__ __forceinline__ void kan_phi(float x, float* v) {
    float b[11];
    #pragma unroll
    for (int i = 0; i < 11; ++i) {
        const float gl = (float)(i - 3) * 0.4f - 1.0f;
        const float gr = (float)(i - 2) * 0.4f - 1.0f;
        b[i] = (x >= gl && x < gr) ? 1.0f : 0.0f;
    }
    #pragma unroll
    for (int k = 1; k <= 3; ++k) {
        #pragma unroll
        for (int i = 0; i + k < 11; ++i) {
            const float gi   = (float)(i - 3) * 0.4f - 1.0f;
            const float gi1  = (float)(i - 2) * 0.4f - 1.0f;
            const float gik  = (float)(i + k - 3) * 0.4f - 1.0f;
            const float gik1 = (float)(i + k - 2) * 0.4f - 1.0f;
            const float invL = 1.0f / (gik - gi);    // constant-folded
            const float invR = 1.0f / (gik1 - gi1);  // constant-folded
            b[i] = (x - gi) * invL * b[i] + (gik1 - x) * invR * b[i + 1];
        }
    }
    v[0] = x > 0.0f ? x : 0.0f;
    #pragma unroll
    for (int i = 0; i < 8; ++i) v[1 + i] = b[i];
}

// ---- fused aux v3 (f-major K layout: k = f*9 + s). One output row per
//      block, built in an LDS row image W[9*FP], then copied out with
//      fully-coalesced ushort8 stores (consecutive lanes -> consecutive
//      16 B). ALL global reads are lane-consecutive float4. Scalar u16
//      LDS writes are ~4-way bank-aliased (cheap vs 69 TB/s LDS).
//      Blocks [0,NE): expand activation rows; [NE,..): pack weight rows. ----
template<int FP, int MODE>
__global__ __launch_bounds__(256)
void aux3_kernel(const float* __restrict__ p0,
                 const float* __restrict__ p1,
                 unsigned short* __restrict__ phi,
                 int F, int NE,
                 const float* __restrict__ bw,
                 const float* __restrict__ sw,
                 const float* __restrict__ sc,
                 unsigned short* __restrict__ wt) {
    __shared__ __align__(16) unsigned short W[9 * FP];   // row image
    __shared__ __align__(16) float scL[FP];              // pack: scaler row
    const int tid  = threadIdx.x;
    const int NW8  = (9 * FP) / 8;                       // ushort8s per row

    if ((int)blockIdx.x < NE) {
        // ---------- expand row n ----------
        const int n = blockIdx.x;
        if (MODE == 1) {
            // FP=1024. xs/ys rows: 512 floats = 128 float4 each.
            // threads 0..127 -> xs float4 #q -> even features 8q+2c;
            // threads 128..255 -> ys float4 #q -> odd features 8q+2c+1.
            const int half = tid >> 7;
            const int q    = tid & 127;
            const float* src = half ? p1 : p0;
            const float4 v = *reinterpret_cast<const float4*>(
                src + (size_t)n * NPTS + (size_t)q * 4);
            const float xv[4] = {v.x, v.y, v.z, v.w};
            #pragma unroll
            for (int c = 0; c < 4; ++c) {
                const int f = 8 * q + 2 * c + half;
                float ph[9];
                kan_phi(xv[c], ph);
                const bool valid = f < F;
                #pragma unroll
                for (int s = 0; s < 9; ++s)
                    W[f * 9 + s] = valid ? f2bf(ph[s]) : (unsigned short)0;
            }
        } else {
            // FP=2048. row = 512 float4 per partial; sum two partials.
            #pragma unroll
            for (int r = 0; r < 2; ++r) {
                const int q = tid + r * 256;
                const float4 a = *reinterpret_cast<const float4*>(
                    p0 + (size_t)n * F + (size_t)q * 4);
                const float4 c4 = *reinterpret_cast<const float4*>(
                    p1 + (size_t)n * F + (size_t)q * 4);
                const float xv[4] = {a.x + c4.x, a.y + c4.y, a.z + c4.z, a.w + c4.w};
                #pragma unroll
                for (int c = 0; c < 4; ++c) {
                    const int f = q * 4 + c;
                    float ph[9];
                    kan_phi(xv[c], ph);
                    #pragma unroll
                    for (int s = 0; s < 9; ++s)
                        W[f * 9 + s] = f2bf(ph[s]);
                }
            }
        }
        __syncthreads();
        ushort8* dst = reinterpret_cast<ushort8*>(phi + (size_t)n * (size_t)(9 * FP));
        const ushort8* srcW = reinterpret_cast<const ushort8*>(W);
        for (int idx = tid; idx < NW8; idx += 256) dst[idx] = srcW[idx];
    } else {
        // ---------- pack weight row o ----------
        const int o = blockIdx.x - NE;
        // stage scaler row (tail-guarded float4)
        for (int i = tid; i < FP / 4; i += 256) {
            float4 v;
            if (i * 4 + 4 <= F) {
                v = *reinterpret_cast<const float4*>(sc + (size_t)o * F + (size_t)i * 4);
            } else {
                float tmp[4];
                #pragma unroll
                for (int c = 0; c < 4; ++c)
                    tmp[c] = (i * 4 + c < F) ? sc[(size_t)o * F + i * 4 + c] : 0.0f;
                v = float4{tmp[0], tmp[1], tmp[2], tmp[3]};
            }
            *reinterpret_cast<float4*>(&scL[i * 4]) = v;
        }
        // base_w -> slot 0 (tail-guarded float4)
        for (int i = tid; i < FP / 4; i += 256) {
            float4 v;
            if (i * 4 + 4 <= F) {
                v = *reinterpret_cast<const float4*>(bw + (size_t)o * F + (size_t)i * 4);
            } else {
                float tmp[4];
                #pragma unroll
                for (int c = 0; c < 4; ++c)
                    tmp[c] = (i * 4 + c < F) ? bw[(size_t)o * F + i * 4 + c] : 0.0f;
                v = float4{tmp[0], tmp[1], tmp[2], tmp[3]};
            }
            const float vv[4] = {v.x, v.y, v.z, v.w};
            #pragma unroll
            for (int c = 0; c < 4; ++c) {
                const int f = i * 4 + c;
                W[f * 9] = (f < F) ? f2bf(vv[c]) : (unsigned short)0;
            }
        }
        __syncthreads();   // scL ready before sw consumes it
        // spline_w * scaler -> slots 1..8. sw row = 2*F float4s (8 floats/feat).
        for (int i = tid; i < FP * 2; i += 256) {
            const int f = i >> 1;
            const int h = i & 1;
            float4 v = float4{0.f, 0.f, 0.f, 0.f};
            if (i < 2 * F)
                v = *reinterpret_cast<const float4*>(
                    sw + (size_t)o * F * 8 + (size_t)i * 4);
            const float s = scL[f];
            const float vv[4] = {v.x * s, v.y * s, v.z * s, v.w * s};
            #pragma unroll
            for (int c = 0; c < 4; ++c)
                W[f * 9 + 1 + 4 * h + c] = (f < F) ? f2bf(vv[c]) : (unsigned short)0;
        }
        __syncthreads();
        ushort8* dst = reinterpret_cast<ushort8*>(wt + (size_t)o * (size_t)(9 * FP));
        const ushort8* srcW = reinterpret_cast<const ushort8*>(W);
        for (int idx = tid; idx < NW8; idx += 256) dst[idx] = srcW[idx];
    }
}

// ---- bf16 GEMM: 256x256 tile, BK=64, 8 waves (2M x 4N), 4-phase pipelined
//      schedule (T3+T4): per phase {ds_read subtile || 1 half-tile prefetch ->
//      s_barrier -> lgkmcnt(0) -> setprio(1) 16xMFMA setprio(0) -> s_barrier},
//      counted vmcnt(6) once per K-tile (3 half-tiles in flight, never 0 in
//      main loop). XOR-swizzled LDS via pre-swizzled global source (linear
//      global_load_lds dest). Epilogue uses clamped same-data restage so vmcnt
//      counts stay exact. Split-K via blockIdx.z into per-slice partials.
//      (R2-verified: 288-298 us @ L1, MfmaUtil ~45, 0 bank conflicts.) ----
#define STAGE_H(GB, LB) do { \
    __builtin_amdgcn_global_load_lds((const GLOBAL_AS void*)((GB) + (size_t)r6 * K + scol), \
        (LDS_AS void*)((LB) + wv512), 16, 0, 0); \
    __builtin_amdgcn_global_load_lds((const GLOBAL_AS void*)((GB) + (size_t)(64 + r6) * K + scol), \
        (LDS_AS void*)((LB) + 4096 + wv512), 16, 0, 0); \
} while (0)

__global__ __launch_bounds__(512, 2)
void gemm_bt_256(const unsigned short* __restrict__ A,
                 const unsigned short* __restrict__ B,
                 float* __restrict__ C,
                 int M, int N, int K, int kchunk) {
    __shared__ __align__(16) unsigned short Alds[2 * 16384];  // 2 bufs x 256x64
    __shared__ __align__(16) unsigned short Blds[2 * 16384];

    const int tid  = threadIdx.x;
    const int wv   = tid >> 6;
    const int lane = tid & 63;
    const int fr   = lane & 15;
    const int fq   = lane >> 4;
    const int wmi  = wv >> 2;    // 0..1  (M wave)
    const int wni  = wv & 3;     // 0..3  (N wave)

    const int bm = blockIdx.y;
    const int bn = blockIdx.x;
    const int kbase = blockIdx.z * kchunk;
    const int NT = kchunk >> 6;
    float* Cz = C + (size_t)blockIdx.z * (size_t)M * N;

    // staging geometry: thread t covers row r6, col-slot p=t&7; source col
    // pre-swizzled so linear LDS dest + swizzled ds_read agree (rule #21)
    const int r6    = tid >> 3;                        // 0..63
    const int scol  = ((tid & 7) ^ (r6 & 7)) * 8;      // k-elem offset
    const int wv512 = wv * 512;                        // lds elems per wave

    const unsigned short* Ab = A + (size_t)bm * 256 * K;
    const unsigned short* Bb = B + (size_t)bn * 256 * K;

    // ds_read fragment offsets (elems); row&7 == fr&7 for all frags
    const int aoff0 = (wmi * 16 + fr) * 64 + ((fq    ) ^ (fr & 7)) * 8;
    const int aoff1 = (wmi * 16 + fr) * 64 + ((4 + fq) ^ (fr & 7)) * 8;
    const int boff0 = (wni * 16 + fr) * 64 + ((fq    ) ^ (fr & 7)) * 8;
    const int boff1 = (wni * 16 + fr) * 64 + ((4 + fq) ^ (fr & 7)) * 8;

    floatx4 zero = {0.f, 0.f, 0.f, 0.f};
    floatx4 acc[8][4];
    #pragma unroll
    for (int i = 0; i < 8; ++i)
        #pragma unroll
        for (int j = 0; j < 4; ++j)
            acc[i][j] = zero;

    // ---- prologue: tile0 (B0,A0,B1,A1) + tile1 (B0,A0,B1) = 14 loads ----
    {
        const unsigned short* Ag = Ab + kbase;
        const unsigned short* Bg = Bb + kbase;
        STAGE_H(Bg,                   Blds);                 // B0 t0
        STAGE_H(Ag,                   Alds);                 // A0 t0
        STAGE_H(Bg + (size_t)128 * K, Blds + 8192);          // B1 t0
        STAGE_H(Ag + (size_t)128 * K, Alds + 8192);          // A1 t0
        STAGE_H(Bg + 64,                   Blds + 16384);         // B0 t1
        STAGE_H(Ag + 64,                   Alds + 16384);         // A0 t1
        STAGE_H(Bg + (size_t)128 * K + 64, Blds + 16384 + 8192);  // B1 t1
    }
    asm volatile("s_waitcnt vmcnt(6)" ::: "memory");   // tile0 landed
    __builtin_amdgcn_s_barrier();

    for (int t = 0; t < NT; ++t) {
        unsigned short* Ac = Alds + (t & 1) * 16384;
        unsigned short* Bc = Blds + (t & 1) * 16384;
        const int t1 = (t + 1 < NT) ? t + 1 : NT - 1;   // clamp: same-data restage
        const int t2 = (t + 2 < NT) ? t + 2 : NT - 1;
        const unsigned short* Ag1 = Ab + kbase + t1 * 64;
        const unsigned short* Ag2 = Ab + kbase + t2 * 64;
        const unsigned short* Bg2 = Bb + kbase + t2 * 64;
        unsigned short* Al1 = Alds + (t1 & 1) * 16384;
        unsigned short* Al2 = Alds + (t2 & 1) * 16384;
        unsigned short* Bl2 = Blds + (t2 & 1) * 16384;

        bf16x8 a_lo[4][2], a_hi[4][2], b_lo[2][2], b_hi[2][2];

        // ---------- phase 1: read A0+B0, stage A1(t1), MFMA mt0-3 x nt0-1 ----
        #pragma unroll
        for (int mt = 0; mt < 4; ++mt) {
            a_lo[mt][0] = *reinterpret_cast<const bf16x8*>(Ac + mt * 2048 + aoff0);
            a_lo[mt][1] = *reinterpret_cast<const bf16x8*>(Ac + mt * 2048 + aoff1);
        }
        #pragma unroll
        for (int nt = 0; nt < 2; ++nt) {
            b_lo[nt][0] = *reinterpret_cast<const bf16x8*>(Bc + nt * 4096 + boff0);
            b_lo[nt][1] = *reinterpret_cast<const bf16x8*>(Bc + nt * 4096 + boff1);
        }
        STAGE_H(Ag1 + (size_t)128 * K, Al1 + 8192);          // A1(t+1)
        __builtin_amdgcn_s_barrier();
        asm volatile("s_waitcnt lgkmcnt(0)" ::: "memory");
        __builtin_amdgcn_s_setprio(1);
        #pragma unroll
        for (int mt = 0; mt < 4; ++mt)
            #pragma unroll
            for (int nt = 0; nt < 2; ++nt) {
                acc[mt][nt] = __builtin_amdgcn_mfma_f32_16x16x32_bf16(a_lo[mt][0], b_lo[nt][0], acc[mt][nt], 0, 0, 0);
                acc[mt][nt] = __builtin_amdgcn_mfma_f32_16x16x32_bf16(a_lo[mt][1], b_lo[nt][1], acc[mt][nt], 0, 0, 0);
            }
        __builtin_amdgcn_s_setprio(0);
        __builtin_amdgcn_s_barrier();

        // ---------- phase 2: read B1, stage B0(t2), MFMA mt0-3 x nt2-3 ----
        #pragma unroll
        for (int nt = 0; nt < 2; ++nt) {
            b_hi[nt][0] = *reinterpret_cast<const bf16x8*>(Bc + (2 + nt) * 4096 + boff0);
            b_hi[nt][1] = *reinterpret_cast<const bf16x8*>(Bc + (2 + nt) * 4096 + boff1);
        }
        STAGE_H(Bg2, Bl2);                                   // B0(t+2)
        __builtin_amdgcn_s_barrier();
        asm volatile("s_waitcnt lgkmcnt(0)" ::: "memory");
        __builtin_amdgcn_s_setprio(1);
        #pragma unroll
        for (int mt = 0; mt < 4; ++mt)
            #pragma unroll
            for (int nt = 0; nt < 2; ++nt) {
                acc[mt][2 + nt] = __builtin_amdgcn_mfma_f32_16x16x32_bf16(a_lo[mt][0], b_hi[nt][0], acc[mt][2 + nt], 0, 0, 0);
                acc[mt][2 + nt] = __builtin_amdgcn_mfma_f32_16x16x32_bf16(a_lo[mt][1], b_hi[nt][1], acc[mt][2 + nt], 0, 0, 0);
            }
        __builtin_amdgcn_s_setprio(0);
        __builtin_amdgcn_s_barrier();

        // ---------- phase 3: read A1, stage A0(t2), MFMA mt4-7 x nt0-1 ----
        #pragma unroll
        for (int mt = 0; mt < 4; ++mt) {
            a_hi[mt][0] = *reinterpret_cast<const bf16x8*>(Ac + (4 + mt) * 2048 + aoff0);
            a_hi[mt][1] = *reinterpret_cast<const bf16x8*>(Ac + (4 + mt) * 2048 + aoff1);
        }
        STAGE_H(Ag2, Al2);                                   // A0(t+2)
        __builtin_amdgcn_s_barrier();
        asm volatile("s_waitcnt lgkmcnt(0)" ::: "memory");
        __builtin_amdgcn_s_setprio(1);
        #pragma unroll
        for (int mt = 0; mt < 4; ++mt)
            #pragma unroll
            for (int nt = 0; nt < 2; ++nt) {
                acc[4 + mt][nt] = __builtin_amdgcn_mfma_f32_16x16x32_bf16(a_hi[mt][0], b_lo[nt][0], acc[4 + mt][nt], 0, 0, 0);
                acc[4 + mt][nt] = __builtin_amdgcn_mfma_f32_16x16x32_bf16(a_hi[mt][1], b_lo[nt][1], acc[4 + mt][nt], 0, 0, 0);
            }
        __builtin_amdgcn_s_setprio(0);
        __builtin_amdgcn_s_barrier();

        // ---------- phase 4: stage B1(t2), MFMA mt4-7 x nt2-3, vmcnt(6) ----
        STAGE_H(Bg2 + (size_t)128 * K, Bl2 + 8192);          // B1(t+2)
        __builtin_amdgcn_s_barrier();
        __builtin_amdgcn_s_setprio(1);
        #pragma unroll
        for (int mt = 0; mt < 4; ++mt)
            #pragma unroll
            for (int nt = 0; nt < 2; ++nt) {
                acc[4 + mt][2 + nt] = __builtin_amdgcn_mfma_f32_16x16x32_bf16(a_hi[mt][0], b_hi[nt][0], acc[4 + mt][2 + nt], 0, 0, 0);
                acc[4 + mt][2 + nt] = __builtin_amdgcn_mfma_f32_16x16x32_bf16(a_hi[mt][1], b_hi[nt][1], acc[4 + mt][2 + nt], 0, 0, 0);
            }
        __builtin_amdgcn_s_setprio(0);
        // tile t+1 fully landed; B0/A0/B1 of t+2 (6 loads) stay in flight
        asm volatile("s_waitcnt vmcnt(6)" ::: "memory");
        __builtin_amdgcn_s_barrier();
    }

    // ---- epilogue: C layout col=fr, row=fq*4+r (verified mapping) ----
    #pragma unroll
    for (int mt = 0; mt < 8; ++mt) {
        #pragma unroll
        for (int nt = 0; nt < 4; ++nt) {
            #pragma unroll
            for (int r = 0; r < 4; ++r) {
                int gr = bm * 256 + mt * 32 + wmi * 16 + fq * 4 + r;
                int gc = bn * 256 + nt * 64 + wni * 16 + fr;
                Cz[(size_t)gr * N + gc] = acc[mt][nt][r];
            }
        }
    }
}

// ---- layer-2 fixup: out = sum of 8 k-slice partials ----
__global__ void add8_kernel(const float* __restrict__ p,
                            float* __restrict__ out, int n4, int slice4) {
    int i = blockIdx.x * blockDim.x + threadIdx.x;
    if (i >= n4) return;
    const float4* p4 = reinterpret_cast<const float4*>(p);
    float4 s = p4[i];
    #pragma unroll
    for (int z = 1; z < 8; ++z) {
        float4 v = p4[(size_t)z * slice4 + i];
        s.x += v.x; s.y += v.y; s.z += v.z; s.w += v.w;
    }
    reinterpret_cast<float4*>(out)[i] = s;
}

extern "C" void kernel_launch(void* const* d_in, const int* in_sizes, int n_in,
                              void* d_out, int out_size, void* d_ws, size_t ws_size,
                              hipStream_t stream) {
    const float* xs  = (const float*)d_in[0];
    const float* ys  = (const float*)d_in[1];
    const float* bw0 = (const float*)d_in[2];
    const float* sw0 = (const float*)d_in[3];
    const float* sc0 = (const float*)d_in[4];
    const float* bw1 = (const float*)d_in[5];
    const float* sw1 = (const float*)d_in[6];
    const float* sc1 = (const float*)d_in[7];
    const float* bw2 = (const float*)d_in[8];
    const float* sw2 = (const float*)d_in[9];
    const float* sc2 = (const float*)d_in[10];

    // workspace: Phi 151.0M | Wt 75.5M | Cpart 67.1M (reused per layer)
    char* ws = (char*)d_ws;
    unsigned short* Phi = (unsigned short*)ws;
    unsigned short* Wt  = (unsigned short*)(ws + 150994944);
    float* Cpart = (float*)(ws + 150994944 + 75497472);
    float* out = (float*)d_out;
    (void)ws_size; (void)in_sizes; (void)n_in; (void)out_size;

    const int T = 256;
    const size_t MN = (size_t)M_BATCH * EMB;

    // ---- layer 0: 4096 x 9216 x 2048, split-K=2 ----
    aux3_kernel<F0P, 1><<<M_BATCH + EMB, T, 0, stream>>>(
        xs, ys, Phi, F0, M_BATCH, bw0, sw0, sc0, Wt);
    gemm_bt_256<<<dim3(8, 16, 2), 512, 0, stream>>>(Phi, Wt, Cpart, M_BATCH, EMB, K0, K0 / 2);

    // ---- layer 1: expand fuses p0+p1 partial reduction ----
    aux3_kernel<EMB, 0><<<M_BATCH + EMB, T, 0, stream>>>(
        Cpart, Cpart + MN, Phi, EMB, M_BATCH, bw1, sw1, sc1, Wt);
    gemm_bt_256<<<dim3(8, 16, 2), 512, 0, stream>>>(Phi, Wt, Cpart, M_BATCH, EMB, K12, K12 / 2);

    // ---- layer 2: 4096 x 18432 x 512, split-K=8 ----
    aux3_kernel<EMB, 0><<<M_BATCH + NPTS, T, 0, stream>>>(
        Cpart, Cpart + MN, Phi, EMB, M_BATCH, bw2, sw2, sc2, Wt);
    gemm_bt_256<<<dim3(2, 16, 8), 512, 0, stream>>>(Phi, Wt, Cpart, M_BATCH, NPTS, K12, K12 / 8);
    add8_kernel<<<(M_BATCH * NPTS / 4 + T - 1) / T, T, 0, stream>>>(
        Cpart, out, M_BATCH * NPTS / 4, M_BATCH * NPTS / 4);
}

// Round 6
// 912.990 us; speedup vs baseline: 1.4436x; 1.0083x over previous
//
#include <hip/hip_runtime.h>

#define GLOBAL_AS __attribute__((address_space(1)))
#define LDS_AS    __attribute__((address_space(3)))

typedef __bf16 bf16x8 __attribute__((ext_vector_type(8)));
typedef float  floatx4 __attribute__((ext_vector_type(4)));
typedef unsigned short ushort8 __attribute__((ext_vector_type(8)));

static constexpr int M_BATCH = 4096;
static constexpr int NPTS    = 512;
static constexpr int EMB     = 2048;
static constexpr int F0      = 1023;     // 2*NPTS-1
static constexpr int F0P     = 1024;     // padded feature count, K multiple of 64
static constexpr int K0      = 9 * F0P;  // 9216
static constexpr int K12     = 9 * EMB;  // 18432

// ---- float -> bf16 round-to-nearest-even ----
__device__ __forceinline__ unsigned short f2bf(float f) {
    unsigned int u = __float_as_uint(f);
    u += 0x7fffu + ((u >> 16) & 1u);
    return (unsigned short)(u >> 16);
}

// ---- relu + 8 cubic B-spline bases, mirroring the reference recursion.
//      All grid values are compile-time constants, so the divides fold to
//      constant reciprocal multiplies (0 runtime v_div sequences). ----
__device__ __forceinline__ void kan_phi(float x, float* v) {
    float b[11];
    #pragma unroll
    for (int i = 0; i < 11; ++i) {
        const float gl = (float)(i - 3) * 0.4f - 1.0f;
        const float gr = (float)(i - 2) * 0.4f - 1.0f;
        b[i] = (x >= gl && x < gr) ? 1.0f : 0.0f;
    }
    #pragma unroll
    for (int k = 1; k <= 3; ++k) {
        #pragma unroll
        for (int i = 0; i + k < 11; ++i) {
            const float gi   = (float)(i - 3) * 0.4f - 1.0f;
            const float gi1  = (float)(i - 2) * 0.4f - 1.0f;
            const float gik  = (float)(i + k - 3) * 0.4f - 1.0f;
            const float gik1 = (float)(i + k - 2) * 0.4f - 1.0f;
            const float invL = 1.0f / (gik - gi);    // constant-folded
            const float invR = 1.0f / (gik1 - gi1);  // constant-folded
            b[i] = (x - gi) * invL * b[i] + (gik1 - x) * invR * b[i + 1];
        }
    }
    v[0] = x > 0.0f ? x : 0.0f;
    #pragma unroll
    for (int i = 0; i < 8; ++i) v[1 + i] = b[i];
}

// ---- fused aux v3 (f-major K layout: k = f*9 + s). One output row per
//      block, built in an LDS row image W[9*FP], then copied out with
//      fully-coalesced ushort8 stores. ALL global reads lane-consecutive
//      float4. (R5-verified numerics.) ----
template<int FP, int MODE>
__global__ __launch_bounds__(256)
void aux3_kernel(const float* __restrict__ p0,
                 const float* __restrict__ p1,
                 unsigned short* __restrict__ phi,
                 int F, int NE,
                 const float* __restrict__ bw,
                 const float* __restrict__ sw,
                 const float* __restrict__ sc,
                 unsigned short* __restrict__ wt) {
    __shared__ __align__(16) unsigned short W[9 * FP];   // row image
    __shared__ __align__(16) float scL[FP];              // pack: scaler row
    const int tid  = threadIdx.x;
    const int NW8  = (9 * FP) / 8;                       // ushort8s per row

    if ((int)blockIdx.x < NE) {
        // ---------- expand row n ----------
        const int n = blockIdx.x;
        if (MODE == 1) {
            const int half = tid >> 7;
            const int q    = tid & 127;
            const float* src = half ? p1 : p0;
            const float4 v = *reinterpret_cast<const float4*>(
                src + (size_t)n * NPTS + (size_t)q * 4);
            const float xv[4] = {v.x, v.y, v.z, v.w};
            #pragma unroll
            for (int c = 0; c < 4; ++c) {
                const int f = 8 * q + 2 * c + half;
                float ph[9];
                kan_phi(xv[c], ph);
                const bool valid = f < F;
                #pragma unroll
                for (int s = 0; s < 9; ++s)
                    W[f * 9 + s] = valid ? f2bf(ph[s]) : (unsigned short)0;
            }
        } else {
            #pragma unroll
            for (int r = 0; r < 2; ++r) {
                const int q = tid + r * 256;
                const float4 a = *reinterpret_cast<const float4*>(
                    p0 + (size_t)n * F + (size_t)q * 4);
                const float4 c4 = *reinterpret_cast<const float4*>(
                    p1 + (size_t)n * F + (size_t)q * 4);
                const float xv[4] = {a.x + c4.x, a.y + c4.y, a.z + c4.z, a.w + c4.w};
                #pragma unroll
                for (int c = 0; c < 4; ++c) {
                    const int f = q * 4 + c;
                    float ph[9];
                    kan_phi(xv[c], ph);
                    #pragma unroll
                    for (int s = 0; s < 9; ++s)
                        W[f * 9 + s] = f2bf(ph[s]);
                }
            }
        }
        __syncthreads();
        ushort8* dst = reinterpret_cast<ushort8*>(phi + (size_t)n * (size_t)(9 * FP));
        const ushort8* srcW = reinterpret_cast<const ushort8*>(W);
        for (int idx = tid; idx < NW8; idx += 256) dst[idx] = srcW[idx];
    } else {
        // ---------- pack weight row o ----------
        const int o = blockIdx.x - NE;
        for (int i = tid; i < FP / 4; i += 256) {
            float4 v;
            if (i * 4 + 4 <= F) {
                v = *reinterpret_cast<const float4*>(sc + (size_t)o * F + (size_t)i * 4);
            } else {
                float tmp[4];
                #pragma unroll
                for (int c = 0; c < 4; ++c)
                    tmp[c] = (i * 4 + c < F) ? sc[(size_t)o * F + i * 4 + c] : 0.0f;
                v = float4{tmp[0], tmp[1], tmp[2], tmp[3]};
            }
            *reinterpret_cast<float4*>(&scL[i * 4]) = v;
        }
        for (int i = tid; i < FP / 4; i += 256) {
            float4 v;
            if (i * 4 + 4 <= F) {
                v = *reinterpret_cast<const float4*>(bw + (size_t)o * F + (size_t)i * 4);
            } else {
                float tmp[4];
                #pragma unroll
                for (int c = 0; c < 4; ++c)
                    tmp[c] = (i * 4 + c < F) ? bw[(size_t)o * F + i * 4 + c] : 0.0f;
                v = float4{tmp[0], tmp[1], tmp[2], tmp[3]};
            }
            const float vv[4] = {v.x, v.y, v.z, v.w};
            #pragma unroll
            for (int c = 0; c < 4; ++c) {
                const int f = i * 4 + c;
                W[f * 9] = (f < F) ? f2bf(vv[c]) : (unsigned short)0;
            }
        }
        __syncthreads();   // scL ready before sw consumes it
        for (int i = tid; i < FP * 2; i += 256) {
            const int f = i >> 1;
            const int h = i & 1;
            float4 v = float4{0.f, 0.f, 0.f, 0.f};
            if (i < 2 * F)
                v = *reinterpret_cast<const float4*>(
                    sw + (size_t)o * F * 8 + (size_t)i * 4);
            const float s = scL[f];
            const float vv[4] = {v.x * s, v.y * s, v.z * s, v.w * s};
            #pragma unroll
            for (int c = 0; c < 4; ++c)
                W[f * 9 + 1 + 4 * h + c] = (f < F) ? f2bf(vv[c]) : (unsigned short)0;
        }
        __syncthreads();
        ushort8* dst = reinterpret_cast<ushort8*>(wt + (size_t)o * (size_t)(9 * FP));
        const ushort8* srcW = reinterpret_cast<const ushort8*>(W);
        for (int idx = tid; idx < NW8; idx += 256) dst[idx] = srcW[idx];
    }
}

// ---- bf16 GEMM: 256x256 tile, BK=64, 8 waves (2M x 4N), 4-phase pipelined.
//      R6 change (one lever): REMOVED the mid-phase barrier and the explicit
//      lgkmcnt(0) — fragment loads are plain loads, so the compiler emits
//      counted lgkmcnt per dependent MFMA; DS reads and MFMA now overlap
//      within and across waves instead of strictly alternating (alternation
//      was capping MfmaUtil at ~46%). Phase = {ds_reads || stage -> setprio
//      MFMA -> closing barrier}; 4 barriers/K-tile (was 8). Safety: every
//      fragment is consumed in-phase, so a wave at its closing barrier has
//      all reads complete; each STAGE targets a region whose readers are
//      >=1 closing barrier earlier (A1: t-1 ph3; B0/A0: t ph1; B1: t ph2).
//      Counted vmcnt(6) once per K-tile unchanged. ----
#define STAGE_H(GB, LB) do { \
    __builtin_amdgcn_global_load_lds((const GLOBAL_AS void*)((GB) + (size_t)r6 * K + scol), \
        (LDS_AS void*)((LB) + wv512), 16, 0, 0); \
    __builtin_amdgcn_global_load_lds((const GLOBAL_AS void*)((GB) + (size_t)(64 + r6) * K + scol), \
        (LDS_AS void*)((LB) + 4096 + wv512), 16, 0, 0); \
} while (0)

__global__ __launch_bounds__(512, 2)
void gemm_bt_256(const unsigned short* __restrict__ A,
                 const unsigned short* __restrict__ B,
                 float* __restrict__ C,
                 int M, int N, int K, int kchunk) {
    __shared__ __align__(16) unsigned short Alds[2 * 16384];  // 2 bufs x 256x64
    __shared__ __align__(16) unsigned short Blds[2 * 16384];

    const int tid  = threadIdx.x;
    const int wv   = tid >> 6;
    const int lane = tid & 63;
    const int fr   = lane & 15;
    const int fq   = lane >> 4;
    const int wmi  = wv >> 2;    // 0..1  (M wave)
    const int wni  = wv & 3;     // 0..3  (N wave)

    const int bm = blockIdx.y;
    const int bn = blockIdx.x;
    const int kbase = blockIdx.z * kchunk;
    const int NT = kchunk >> 6;
    float* Cz = C + (size_t)blockIdx.z * (size_t)M * N;

    const int r6    = tid >> 3;                        // 0..63
    const int scol  = ((tid & 7) ^ (r6 & 7)) * 8;      // pre-swizzled k-elem offset
    const int wv512 = wv * 512;

    const unsigned short* Ab = A + (size_t)bm * 256 * K;
    const unsigned short* Bb = B + (size_t)bn * 256 * K;

    const int aoff0 = (wmi * 16 + fr) * 64 + ((fq    ) ^ (fr & 7)) * 8;
    const int aoff1 = (wmi * 16 + fr) * 64 + ((4 + fq) ^ (fr & 7)) * 8;
    const int boff0 = (wni * 16 + fr) * 64 + ((fq    ) ^ (fr & 7)) * 8;
    const int boff1 = (wni * 16 + fr) * 64 + ((4 + fq) ^ (fr & 7)) * 8;

    floatx4 zero = {0.f, 0.f, 0.f, 0.f};
    floatx4 acc[8][4];
    #pragma unroll
    for (int i = 0; i < 8; ++i)
        #pragma unroll
        for (int j = 0; j < 4; ++j)
            acc[i][j] = zero;

    // ---- prologue: tile0 (B0,A0,B1,A1) + tile1 (B0,A0,B1) = 14 loads ----
    {
        const unsigned short* Ag = Ab + kbase;
        const unsigned short* Bg = Bb + kbase;
        STAGE_H(Bg,                   Blds);                 // B0 t0
        STAGE_H(Ag,                   Alds);                 // A0 t0
        STAGE_H(Bg + (size_t)128 * K, Blds + 8192);          // B1 t0
        STAGE_H(Ag + (size_t)128 * K, Alds + 8192);          // A1 t0
        STAGE_H(Bg + 64,                   Blds + 16384);         // B0 t1
        STAGE_H(Ag + 64,                   Alds + 16384);         // A0 t1
        STAGE_H(Bg + (size_t)128 * K + 64, Blds + 16384 + 8192);  // B1 t1
    }
    asm volatile("s_waitcnt vmcnt(6)" ::: "memory");   // tile0 landed
    __builtin_amdgcn_s_barrier();

    for (int t = 0; t < NT; ++t) {
        unsigned short* Ac = Alds + (t & 1) * 16384;
        unsigned short* Bc = Blds + (t & 1) * 16384;
        const int t1 = (t + 1 < NT) ? t + 1 : NT - 1;   // clamp: same-data restage
        const int t2 = (t + 2 < NT) ? t + 2 : NT - 1;
        const unsigned short* Ag1 = Ab + kbase + t1 * 64;
        const unsigned short* Ag2 = Ab + kbase + t2 * 64;
        const unsigned short* Bg2 = Bb + kbase + t2 * 64;
        unsigned short* Al1 = Alds + (t1 & 1) * 16384;
        unsigned short* Al2 = Alds + (t2 & 1) * 16384;
        unsigned short* Bl2 = Blds + (t2 & 1) * 16384;

        bf16x8 a_lo[4][2], a_hi[4][2], b_lo[2][2], b_hi[2][2];

        // ---------- phase 1: read A0+B0 || stage A1(t1) -> MFMA mt0-3 x nt0-1 ----
        #pragma unroll
        for (int mt = 0; mt < 4; ++mt) {
            a_lo[mt][0] = *reinterpret_cast<const bf16x8*>(Ac + mt * 2048 + aoff0);
            a_lo[mt][1] = *reinterpret_cast<const bf16x8*>(Ac + mt * 2048 + aoff1);
        }
        #pragma unroll
        for (int nt = 0; nt < 2; ++nt) {
            b_lo[nt][0] = *reinterpret_cast<const bf16x8*>(Bc + nt * 4096 + boff0);
            b_lo[nt][1] = *reinterpret_cast<const bf16x8*>(Bc + nt * 4096 + boff1);
        }
        STAGE_H(Ag1 + (size_t)128 * K, Al1 + 8192);          // A1(t+1)
        __builtin_amdgcn_s_setprio(1);
        #pragma unroll
        for (int mt = 0; mt < 4; ++mt)
            #pragma unroll
            for (int nt = 0; nt < 2; ++nt) {
                acc[mt][nt] = __builtin_amdgcn_mfma_f32_16x16x32_bf16(a_lo[mt][0], b_lo[nt][0], acc[mt][nt], 0, 0, 0);
                acc[mt][nt] = __builtin_amdgcn_mfma_f32_16x16x32_bf16(a_lo[mt][1], b_lo[nt][1], acc[mt][nt], 0, 0, 0);
            }
        __builtin_amdgcn_s_setprio(0);
        __builtin_amdgcn_s_barrier();

        // ---------- phase 2: read B1 || stage B0(t2) -> MFMA mt0-3 x nt2-3 ----
        #pragma unroll
        for (int nt = 0; nt < 2; ++nt) {
            b_hi[nt][0] = *reinterpret_cast<const bf16x8*>(Bc + (2 + nt) * 4096 + boff0);
            b_hi[nt][1] = *reinterpret_cast<const bf16x8*>(Bc + (2 + nt) * 4096 + boff1);
        }
        STAGE_H(Bg2, Bl2);                                   // B0(t+2)
        __builtin_amdgcn_s_setprio(1);
        #pragma unroll
        for (int mt = 0; mt < 4; ++mt)
            #pragma unroll
            for (int nt = 0; nt < 2; ++nt) {
                acc[mt][2 + nt] = __builtin_amdgcn_mfma_f32_16x16x32_bf16(a_lo[mt][0], b_hi[nt][0], acc[mt][2 + nt], 0, 0, 0);
                acc[mt][2 + nt] = __builtin_amdgcn_mfma_f32_16x16x32_bf16(a_lo[mt][1], b_hi[nt][1], acc[mt][2 + nt], 0, 0, 0);
            }
        __builtin_amdgcn_s_setprio(0);
        __builtin_amdgcn_s_barrier();

        // ---------- phase 3: read A1 || stage A0(t2) -> MFMA mt4-7 x nt0-1 ----
        #pragma unroll
        for (int mt = 0; mt < 4; ++mt) {
            a_hi[mt][0] = *reinterpret_cast<const bf16x8*>(Ac + (4 + mt) * 2048 + aoff0);
            a_hi[mt][1] = *reinterpret_cast<const bf16x8*>(Ac + (4 + mt) * 2048 + aoff1);
        }
        STAGE_H(Ag2, Al2);                                   // A0(t+2)
        __builtin_amdgcn_s_setprio(1);
        #pragma unroll
        for (int mt = 0; mt < 4; ++mt)
            #pragma unroll
            for (int nt = 0; nt < 2; ++nt) {
                acc[4 + mt][nt] = __builtin_amdgcn_mfma_f32_16x16x32_bf16(a_hi[mt][0], b_lo[nt][0], acc[4 + mt][nt], 0, 0, 0);
                acc[4 + mt][nt] = __builtin_amdgcn_mfma_f32_16x16x32_bf16(a_hi[mt][1], b_lo[nt][1], acc[4 + mt][nt], 0, 0, 0);
            }
        __builtin_amdgcn_s_setprio(0);
        __builtin_amdgcn_s_barrier();

        // ---------- phase 4: stage B1(t2) -> MFMA mt4-7 x nt2-3, vmcnt(6) ----
        STAGE_H(Bg2 + (size_t)128 * K, Bl2 + 8192);          // B1(t+2)
        __builtin_amdgcn_s_setprio(1);
        #pragma unroll
        for (int mt = 0; mt < 4; ++mt)
            #pragma unroll
            for (int nt = 0; nt < 2; ++nt) {
                acc[4 + mt][2 + nt] = __builtin_amdgcn_mfma_f32_16x16x32_bf16(a_hi[mt][0], b_hi[nt][0], acc[4 + mt][2 + nt], 0, 0, 0);
                acc[4 + mt][2 + nt] = __builtin_amdgcn_mfma_f32_16x16x32_bf16(a_hi[mt][1], b_hi[nt][1], acc[4 + mt][2 + nt], 0, 0, 0);
            }
        __builtin_amdgcn_s_setprio(0);
        // tile t+1 fully landed; B0/A0/B1 of t+2 (6 loads) stay in flight
        asm volatile("s_waitcnt vmcnt(6)" ::: "memory");
        __builtin_amdgcn_s_barrier();
    }

    // ---- epilogue: C layout col=fr, row=fq*4+r (verified mapping) ----
    #pragma unroll
    for (int mt = 0; mt < 8; ++mt) {
        #pragma unroll
        for (int nt = 0; nt < 4; ++nt) {
            #pragma unroll
            for (int r = 0; r < 4; ++r) {
                int gr = bm * 256 + mt * 32 + wmi * 16 + fq * 4 + r;
                int gc = bn * 256 + nt * 64 + wni * 16 + fr;
                Cz[(size_t)gr * N + gc] = acc[mt][nt][r];
            }
        }
    }
}

// ---- layer-2 fixup: out = sum of 8 k-slice partials ----
__global__ void add8_kernel(const float* __restrict__ p,
                            float* __restrict__ out, int n4, int slice4) {
    int i = blockIdx.x * blockDim.x + threadIdx.x;
    if (i >= n4) return;
    const float4* p4 = reinterpret_cast<const float4*>(p);
    float4 s = p4[i];
    #pragma unroll
    for (int z = 1; z < 8; ++z) {
        float4 v = p4[(size_t)z * slice4 + i];
        s.x += v.x; s.y += v.y; s.z += v.z; s.w += v.w;
    }
    reinterpret_cast<float4*>(out)[i] = s;
}

extern "C" void kernel_launch(void* const* d_in, const int* in_sizes, int n_in,
                              void* d_out, int out_size, void* d_ws, size_t ws_size,
                              hipStream_t stream) {
    const float* xs  = (const float*)d_in[0];
    const float* ys  = (const float*)d_in[1];
    const float* bw0 = (const float*)d_in[2];
    const float* sw0 = (const float*)d_in[3];
    const float* sc0 = (const float*)d_in[4];
    const float* bw1 = (const float*)d_in[5];
    const float* sw1 = (const float*)d_in[6];
    const float* sc1 = (const float*)d_in[7];
    const float* bw2 = (const float*)d_in[8];
    const float* sw2 = (const float*)d_in[9];
    const float* sc2 = (const float*)d_in[10];

    // workspace: Phi 151.0M | Wt 75.5M | Cpart 67.1M (reused per layer)
    char* ws = (char*)d_ws;
    unsigned short* Phi = (unsigned short*)ws;
    unsigned short* Wt  = (unsigned short*)(ws + 150994944);
    float* Cpart = (float*)(ws + 150994944 + 75497472);
    float* out = (float*)d_out;
    (void)ws_size; (void)in_sizes; (void)n_in; (void)out_size;

    const int T = 256;
    const size_t MN = (size_t)M_BATCH * EMB;

    // ---- layer 0: 4096 x 9216 x 2048, split-K=2 ----
    aux3_kernel<F0P, 1><<<M_BATCH + EMB, T, 0, stream>>>(
        xs, ys, Phi, F0, M_BATCH, bw0, sw0, sc0, Wt);
    gemm_bt_256<<<dim3(8, 16, 2), 512, 0, stream>>>(Phi, Wt, Cpart, M_BATCH, EMB, K0, K0 / 2);

    // ---- layer 1: expand fuses p0+p1 partial reduction ----
    aux3_kernel<EMB, 0><<<M_BATCH + EMB, T, 0, stream>>>(
        Cpart, Cpart + MN, Phi, EMB, M_BATCH, bw1, sw1, sc1, Wt);
    gemm_bt_256<<<dim3(8, 16, 2), 512, 0, stream>>>(Phi, Wt, Cpart, M_BATCH, EMB, K12, K12 / 2);

    // ---- layer 2: 4096 x 18432 x 512, split-K=8 ----
    aux3_kernel<EMB, 0><<<M_BATCH + NPTS, T, 0, stream>>>(
        Cpart, Cpart + MN, Phi, EMB, M_BATCH, bw2, sw2, sc2, Wt);
    gemm_bt_256<<<dim3(2, 16, 8), 512, 0, stream>>>(Phi, Wt, Cpart, M_BATCH, NPTS, K12, K12 / 8);
    add8_kernel<<<(M_BATCH * NPTS / 4 + T - 1) / T, T, 0, stream>>>(
        Cpart, out, M_BATCH * NPTS / 4, M_BATCH * NPTS / 4);
}

// Round 8
// 903.109 us; speedup vs baseline: 1.4594x; 1.0109x over previous
//
#include <hip/hip_runtime.h>

#define GLOBAL_AS __attribute__((address_space(1)))
#define LDS_AS    __attribute__((address_space(3)))

typedef __bf16 bf16x8 __attribute__((ext_vector_type(8)));
typedef float  floatx4 __attribute__((ext_vector_type(4)));
typedef unsigned short ushort8 __attribute__((ext_vector_type(8)));
typedef unsigned short ushort4v __attribute__((ext_vector_type(4)));

static constexpr int M_BATCH = 4096;
static constexpr int NPTS    = 512;
static constexpr int EMB     = 2048;
static constexpr int F0      = 1023;     // 2*NPTS-1
static constexpr int F0P     = 1024;     // padded feature count, K multiple of 64
static constexpr int K0      = 9 * F0P;  // 9216
static constexpr int K12     = 9 * EMB;  // 18432

// ---- float -> bf16 round-to-nearest-even ----
__device__ __forceinline__ unsigned short f2bf(float f) {
    unsigned int u = __float_as_uint(f);
    u += 0x7fffu + ((u >> 16) & 1u);
    return (unsigned short)(u >> 16);
}

// ---- closed-form cubic B-spline emit: for 4 consecutive features, write
//      the 9-slot strip {relu, b0..b7} into the LDS row image. Only 4 bases
//      are non-zero (support width 4): interval m = floor((x+2.2)*2.5),
//      local t in [0,1); values are the uniform cubic pieces /6 scattered
//      to slots m-3..m (range-guarded). x outside [-2.2,2.2) -> all zero,
//      matching the reference recursion's indicator semantics. C^2
//      continuity makes knot-edge m ambiguity harmless (~1 ulp f32). ----
__device__ __forceinline__ void emit4(unsigned short* W, int f0,
                                      const float* xv, int F) {
    // pre-zero the 36-u16 strip (8B-aligned: byte 18*f0, f0 % 4 == 0)
    const ushort4v z4 = {0, 0, 0, 0};
    #pragma unroll
    for (int j = 0; j < 9; ++j)
        *reinterpret_cast<ushort4v*>(&W[f0 * 9 + j * 4]) = z4;
    #pragma unroll
    for (int c = 0; c < 4; ++c) {
        const int f = f0 + c;
        if (f >= F) continue;
        const float x = xv[c];
        W[f * 9] = f2bf(x > 0.0f ? x : 0.0f);
        const int m = (int)floorf((x + 2.2f) * 2.5f);
        if (m >= 0 && m <= 10) {
            const float gm = (float)(m - 3) * 0.4f - 1.0f;  // reference knot
            const float t  = (x - gm) * 2.5f;
            const float u  = 1.0f - t;
            const float t2 = t * t, t3 = t2 * t;
            const float s6 = 1.0f / 6.0f;
            float Nv[4];
            Nv[0] = u * u * u * s6;                              // slot m-3
            Nv[1] = (3.0f * t3 - 6.0f * t2 + 4.0f) * s6;         // slot m-2
            Nv[2] = (-3.0f * t3 + 3.0f * t2 + 3.0f * t + 1.0f) * s6; // m-1
            Nv[3] = t3 * s6;                                     // slot m
            #pragma unroll
            for (int r = 0; r < 4; ++r) {
                const int idx = m - 3 + r;
                if (idx >= 0 && idx <= 7)
                    W[f * 9 + 1 + idx] = f2bf(Nv[r]);
            }
        }
    }
}

// ---- expand: one activation row per block, f-major K layout (k = f*9+s).
//      Row image built in LDS, copied out fully coalesced (ushort8).
//      MODE 1: interleave xs/ys (thread owns 4 contiguous features via two
//      float2 loads). MODE 0: sum two split-K partials (float4 loads). ----
template<int FP, int MODE>
__global__ __launch_bounds__(256)
void expand4_kernel(const float* __restrict__ p0,
                    const float* __restrict__ p1,
                    unsigned short* __restrict__ phi, int F) {
    __shared__ __align__(16) unsigned short W[9 * FP];
    const int tid = threadIdx.x;
    const int n   = blockIdx.x;
    constexpr int NW8 = (9 * FP) / 8;

    if (MODE == 1) {
        // FP=1024: f = 4*tid + {0,1,2,3} -> xs[2t], ys[2t], xs[2t+1], ys[2t+1]
        const float2 xsv = *reinterpret_cast<const float2*>(
            p0 + (size_t)n * NPTS + 2 * tid);
        const float2 ysv = *reinterpret_cast<const float2*>(
            p1 + (size_t)n * NPTS + 2 * tid);
        float xv[4] = {xsv.x, ysv.x, xsv.y, ysv.y};
        emit4(W, 4 * tid, xv, F);
    } else {
        #pragma unroll
        for (int r = 0; r < FP / 1024; ++r) {
            const int q = tid + r * 256;
            const float4 a = *reinterpret_cast<const float4*>(
                p0 + (size_t)n * F + (size_t)q * 4);
            const float4 c4 = *reinterpret_cast<const float4*>(
                p1 + (size_t)n * F + (size_t)q * 4);
            float xv[4] = {a.x + c4.x, a.y + c4.y, a.z + c4.z, a.w + c4.w};
            emit4(W, 4 * q, xv, F);
        }
    }
    __syncthreads();
    ushort8* dst = reinterpret_cast<ushort8*>(phi + (size_t)n * (size_t)(9 * FP));
    const ushort8* srcW = reinterpret_cast<const ushort8*>(W);
    #pragma unroll
    for (int idx = tid; idx < NW8; idx += 256) dst[idx] = srcW[idx];
}

// ---- pack: one weight row per block (R5-verified numerics, unchanged
//      math). Coalesced float4 reads, LDS row image, coalesced copy-out. ----
template<int FP>
__global__ __launch_bounds__(256)
void pack4_kernel(const float* __restrict__ bw,
                  const float* __restrict__ sw,
                  const float* __restrict__ sc,
                  unsigned short* __restrict__ wt, int F) {
    __shared__ __align__(16) unsigned short W[9 * FP];
    __shared__ __align__(16) float scL[FP];
    const int tid = threadIdx.x;
    const int o   = blockIdx.x;
    constexpr int NW8 = (9 * FP) / 8;

    for (int i = tid; i < FP / 4; i += 256) {
        float4 v;
        if (i * 4 + 4 <= F) {
            v = *reinterpret_cast<const float4*>(sc + (size_t)o * F + (size_t)i * 4);
        } else {
            float tmp[4];
            #pragma unroll
            for (int c = 0; c < 4; ++c)
                tmp[c] = (i * 4 + c < F) ? sc[(size_t)o * F + i * 4 + c] : 0.0f;
            v = float4{tmp[0], tmp[1], tmp[2], tmp[3]};
        }
        *reinterpret_cast<float4*>(&scL[i * 4]) = v;
    }
    for (int i = tid; i < FP / 4; i += 256) {
        float4 v;
        if (i * 4 + 4 <= F) {
            v = *reinterpret_cast<const float4*>(bw + (size_t)o * F + (size_t)i * 4);
        } else {
            float tmp[4];
            #pragma unroll
            for (int c = 0; c < 4; ++c)
                tmp[c] = (i * 4 + c < F) ? bw[(size_t)o * F + i * 4 + c] : 0.0f;
            v = float4{tmp[0], tmp[1], tmp[2], tmp[3]};
        }
        const float vv[4] = {v.x, v.y, v.z, v.w};
        #pragma unroll
        for (int c = 0; c < 4; ++c) {
            const int f = i * 4 + c;
            W[f * 9] = (f < F) ? f2bf(vv[c]) : (unsigned short)0;
        }
    }
    __syncthreads();   // scL ready before sw consumes it
    for (int i = tid; i < FP * 2; i += 256) {
        const int f = i >> 1;
        const int h = i & 1;
        float4 v = float4{0.f, 0.f, 0.f, 0.f};
        if (i < 2 * F)
            v = *reinterpret_cast<const float4*>(
                sw + (size_t)o * F * 8 + (size_t)i * 4);
        const float s = scL[f];
        const float vv[4] = {v.x * s, v.y * s, v.z * s, v.w * s};
        #pragma unroll
        for (int c = 0; c < 4; ++c)
            W[f * 9 + 1 + 4 * h + c] = (f < F) ? f2bf(vv[c]) : (unsigned short)0;
    }
    __syncthreads();
    ushort8* dst = reinterpret_cast<ushort8*>(wt + (size_t)o * (size_t)(9 * FP));
    const ushort8* srcW = reinterpret_cast<const ushort8*>(W);
    #pragma unroll
    for (int idx = tid; idx < NW8; idx += 256) dst[idx] = srcW[idx];
}

// ---- bf16 GEMM: 256x256 tile, BK=64, 8 waves (2M x 4N), 4-phase pipelined,
//      counted vmcnt(6), XOR-swizzled LDS via pre-swizzled global source.
//      (R6-verified: 276 us @ L1, MfmaUtil ~49, 0 bank conflicts.) ----
#define STAGE_H(GB, LB) do { \
    __builtin_amdgcn_global_load_lds((const GLOBAL_AS void*)((GB) + (size_t)r6 * K + scol), \
        (LDS_AS void*)((LB) + wv512), 16, 0, 0); \
    __builtin_amdgcn_global_load_lds((const GLOBAL_AS void*)((GB) + (size_t)(64 + r6) * K + scol), \
        (LDS_AS void*)((LB) + 4096 + wv512), 16, 0, 0); \
} while (0)

__global__ __launch_bounds__(512, 2)
void gemm_bt_256(const unsigned short* __restrict__ A,
                 const unsigned short* __restrict__ B,
                 float* __restrict__ C,
                 int M, int N, int K, int kchunk) {
    __shared__ __align__(16) unsigned short Alds[2 * 16384];  // 2 bufs x 256x64
    __shared__ __align__(16) unsigned short Blds[2 * 16384];

    const int tid  = threadIdx.x;
    const int wv   = tid >> 6;
    const int lane = tid & 63;
    const int fr   = lane & 15;
    const int fq   = lane >> 4;
    const int wmi  = wv >> 2;    // 0..1  (M wave)
    const int wni  = wv & 3;     // 0..3  (N wave)

    const int bm = blockIdx.y;
    const int bn = blockIdx.x;
    const int kbase = blockIdx.z * kchunk;
    const int NT = kchunk >> 6;
    float* Cz = C + (size_t)blockIdx.z * (size_t)M * N;

    const int r6    = tid >> 3;                        // 0..63
    const int scol  = ((tid & 7) ^ (r6 & 7)) * 8;      // pre-swizzled k-elem offset
    const int wv512 = wv * 512;

    const unsigned short* Ab = A + (size_t)bm * 256 * K;
    const unsigned short* Bb = B + (size_t)bn * 256 * K;

    const int aoff0 = (wmi * 16 + fr) * 64 + ((fq    ) ^ (fr & 7)) * 8;
    const int aoff1 = (wmi * 16 + fr) * 64 + ((4 + fq) ^ (fr & 7)) * 8;
    const int boff0 = (wni * 16 + fr) * 64 + ((fq    ) ^ (fr & 7)) * 8;
    const int boff1 = (wni * 16 + fr) * 64 + ((4 + fq) ^ (fr & 7)) * 8;

    floatx4 zero = {0.f, 0.f, 0.f, 0.f};
    floatx4 acc[8][4];
    #pragma unroll
    for (int i = 0; i < 8; ++i)
        #pragma unroll
        for (int j = 0; j < 4; ++j)
            acc[i][j] = zero;

    // ---- prologue: tile0 (B0,A0,B1,A1) + tile1 (B0,A0,B1) = 14 loads ----
    {
        const unsigned short* Ag = Ab + kbase;
        const unsigned short* Bg = Bb + kbase;
        STAGE_H(Bg,                   Blds);                 // B0 t0
        STAGE_H(Ag,                   Alds);                 // A0 t0
        STAGE_H(Bg + (size_t)128 * K, Blds + 8192);          // B1 t0
        STAGE_H(Ag + (size_t)128 * K, Alds + 8192);          // A1 t0
        STAGE_H(Bg + 64,                   Blds + 16384);         // B0 t1
        STAGE_H(Ag + 64,                   Alds + 16384);         // A0 t1
        STAGE_H(Bg + (size_t)128 * K + 64, Blds + 16384 + 8192);  // B1 t1
    }
    asm volatile("s_waitcnt vmcnt(6)" ::: "memory");   // tile0 landed
    __builtin_amdgcn_s_barrier();

    for (int t = 0; t < NT; ++t) {
        unsigned short* Ac = Alds + (t & 1) * 16384;
        unsigned short* Bc = Blds + (t & 1) * 16384;
        const int t1 = (t + 1 < NT) ? t + 1 : NT - 1;   // clamp: same-data restage
        const int t2 = (t + 2 < NT) ? t + 2 : NT - 1;
        const unsigned short* Ag1 = Ab + kbase + t1 * 64;
        const unsigned short* Ag2 = Ab + kbase + t2 * 64;
        const unsigned short* Bg2 = Bb + kbase + t2 * 64;
        unsigned short* Al1 = Alds + (t1 & 1) * 16384;
        unsigned short* Al2 = Alds + (t2 & 1) * 16384;
        unsigned short* Bl2 = Blds + (t2 & 1) * 16384;

        bf16x8 a_lo[4][2], a_hi[4][2], b_lo[2][2], b_hi[2][2];

        // ---------- phase 1: read A0+B0 || stage A1(t1) -> MFMA mt0-3 x nt0-1 ----
        #pragma unroll
        for (int mt = 0; mt < 4; ++mt) {
            a_lo[mt][0] = *reinterpret_cast<const bf16x8*>(Ac + mt * 2048 + aoff0);
            a_lo[mt][1] = *reinterpret_cast<const bf16x8*>(Ac + mt * 2048 + aoff1);
        }
        #pragma unroll
        for (int nt = 0; nt < 2; ++nt) {
            b_lo[nt][0] = *reinterpret_cast<const bf16x8*>(Bc + nt * 4096 + boff0);
            b_lo[nt][1] = *reinterpret_cast<const bf16x8*>(Bc + nt * 4096 + boff1);
        }
        STAGE_H(Ag1 + (size_t)128 * K, Al1 + 8192);          // A1(t+1)
        __builtin_amdgcn_s_setprio(1);
        #pragma unroll
        for (int mt = 0; mt < 4; ++mt)
            #pragma unroll
            for (int nt = 0; nt < 2; ++nt) {
                acc[mt][nt] = __builtin_amdgcn_mfma_f32_16x16x32_bf16(a_lo[mt][0], b_lo[nt][0], acc[mt][nt], 0, 0, 0);
                acc[mt][nt] = __builtin_amdgcn_mfma_f32_16x16x32_bf16(a_lo[mt][1], b_lo[nt][1], acc[mt][nt], 0, 0, 0);
            }
        __builtin_amdgcn_s_setprio(0);
        __builtin_amdgcn_s_barrier();

        // ---------- phase 2: read B1 || stage B0(t2) -> MFMA mt0-3 x nt2-3 ----
        #pragma unroll
        for (int nt = 0; nt < 2; ++nt) {
            b_hi[nt][0] = *reinterpret_cast<const bf16x8*>(Bc + (2 + nt) * 4096 + boff0);
            b_hi[nt][1] = *reinterpret_cast<const bf16x8*>(Bc + (2 + nt) * 4096 + boff1);
        }
        STAGE_H(Bg2, Bl2);                                   // B0(t+2)
        __builtin_amdgcn_s_setprio(1);
        #pragma unroll
        for (int mt = 0; mt < 4; ++mt)
            #pragma unroll
            for (int nt = 0; nt < 2; ++nt) {
                acc[mt][2 + nt] = __builtin_amdgcn_mfma_f32_16x16x32_bf16(a_lo[mt][0], b_hi[nt][0], acc[mt][2 + nt], 0, 0, 0);
                acc[mt][2 + nt] = __builtin_amdgcn_mfma_f32_16x16x32_bf16(a_lo[mt][1], b_hi[nt][1], acc[mt][2 + nt], 0, 0, 0);
            }
        __builtin_amdgcn_s_setprio(0);
        __builtin_amdgcn_s_barrier();

        // ---------- phase 3: read A1 || stage A0(t2) -> MFMA mt4-7 x nt0-1 ----
        #pragma unroll
        for (int mt = 0; mt < 4; ++mt) {
            a_hi[mt][0] = *reinterpret_cast<const bf16x8*>(Ac + (4 + mt) * 2048 + aoff0);
            a_hi[mt][1] = *reinterpret_cast<const bf16x8*>(Ac + (4 + mt) * 2048 + aoff1);
        }
        STAGE_H(Ag2, Al2);                                   // A0(t+2)
        __builtin_amdgcn_s_setprio(1);
        #pragma unroll
        for (int mt = 0; mt < 4; ++mt)
            #pragma unroll
            for (int nt = 0; nt < 2; ++nt) {
                acc[4 + mt][nt] = __builtin_amdgcn_mfma_f32_16x16x32_bf16(a_hi[mt][0], b_lo[nt][0], acc[4 + mt][nt], 0, 0, 0);
                acc[4 + mt][nt] = __builtin_amdgcn_mfma_f32_16x16x32_bf16(a_hi[mt][1], b_lo[nt][1], acc[4 + mt][nt], 0, 0, 0);
            }
        __builtin_amdgcn_s_setprio(0);
        __builtin_amdgcn_s_barrier();

        // ---------- phase 4: stage B1(t2) -> MFMA mt4-7 x nt2-3, vmcnt(6) ----
        STAGE_H(Bg2 + (size_t)128 * K, Bl2 + 8192);          // B1(t+2)
        __builtin_amdgcn_s_setprio(1);
        #pragma unroll
        for (int mt = 0; mt < 4; ++mt)
            #pragma unroll
            for (int nt = 0; nt < 2; ++nt) {
                acc[4 + mt][2 + nt] = __builtin_amdgcn_mfma_f32_16x16x32_bf16(a_hi[mt][0], b_hi[nt][0], acc[4 + mt][2 + nt], 0, 0, 0);
                acc[4 + mt][2 + nt] = __builtin_amdgcn_mfma_f32_16x16x32_bf16(a_hi[mt][1], b_hi[nt][1], acc[4 + mt][2 + nt], 0, 0, 0);
            }
        __builtin_amdgcn_s_setprio(0);
        // tile t+1 fully landed; B0/A0/B1 of t+2 (6 loads) stay in flight
        asm volatile("s_waitcnt vmcnt(6)" ::: "memory");
        __builtin_amdgcn_s_barrier();
    }

    // ---- epilogue: C layout col=fr, row=fq*4+r (verified mapping) ----
    #pragma unroll
    for (int mt = 0; mt < 8; ++mt) {
        #pragma unroll
        for (int nt = 0; nt < 4; ++nt) {
            #pragma unroll
            for (int r = 0; r < 4; ++r) {
                int gr = bm * 256 + mt * 32 + wmi * 16 + fq * 4 + r;
                int gc = bn * 256 + nt * 64 + wni * 16 + fr;
                Cz[(size_t)gr * N + gc] = acc[mt][nt][r];
            }
        }
    }
}

// ---- layer-2 fixup: out = sum of 8 k-slice partials ----
__global__ void add8_kernel(const float* __restrict__ p,
                            float* __restrict__ out, int n4, int slice4) {
    int i = blockIdx.x * blockDim.x + threadIdx.x;
    if (i >= n4) return;
    const float4* p4 = reinterpret_cast<const float4*>(p);
    float4 s = p4[i];
    #pragma unroll
    for (int z = 1; z < 8; ++z) {
        float4 v = p4[(size_t)z * slice4 + i];
        s.x += v.x; s.y += v.y; s.z += v.z; s.w += v.w;
    }
    reinterpret_cast<float4*>(out)[i] = s;
}

extern "C" void kernel_launch(void* const* d_in, const int* in_sizes, int n_in,
                              void* d_out, int out_size, void* d_ws, size_t ws_size,
                              hipStream_t stream) {
    const float* xs  = (const float*)d_in[0];
    const float* ys  = (const float*)d_in[1];
    const float* bw0 = (const float*)d_in[2];
    const float* sw0 = (const float*)d_in[3];
    const float* sc0 = (const float*)d_in[4];
    const float* bw1 = (const float*)d_in[5];
    const float* sw1 = (const float*)d_in[6];
    const float* sc1 = (const float*)d_in[7];
    const float* bw2 = (const float*)d_in[8];
    const float* sw2 = (const float*)d_in[9];
    const float* sc2 = (const float*)d_in[10];

    // workspace: Phi 151.0M | Wt 75.5M | Cpart 67.1M (reused per layer)
    char* ws = (char*)d_ws;
    unsigned short* Phi = (unsigned short*)ws;
    unsigned short* Wt  = (unsigned short*)(ws + 150994944);
    float* Cpart = (float*)(ws + 150994944 + 75497472);
    float* out = (float*)d_out;
    (void)ws_size; (void)in_sizes; (void)n_in; (void)out_size;

    const int T = 256;
    const size_t MN = (size_t)M_BATCH * EMB;

    // ---- layer 0: 4096 x 9216 x 2048, split-K=2 ----
    expand4_kernel<F0P, 1><<<M_BATCH, T, 0, stream>>>(xs, ys, Phi, F0);
    pack4_kernel<F0P><<<EMB, T, 0, stream>>>(bw0, sw0, sc0, Wt, F0);
    gemm_bt_256<<<dim3(8, 16, 2), 512, 0, stream>>>(Phi, Wt, Cpart, M_BATCH, EMB, K0, K0 / 2);

    // ---- layer 1: expand fuses p0+p1 partial reduction ----
    expand4_kernel<EMB, 0><<<M_BATCH, T, 0, stream>>>(Cpart, Cpart + MN, Phi, EMB);
    pack4_kernel<EMB><<<EMB, T, 0, stream>>>(bw1, sw1, sc1, Wt, EMB);
    gemm_bt_256<<<dim3(8, 16, 2), 512, 0, stream>>>(Phi, Wt, Cpart, M_BATCH, EMB, K12, K12 / 2);

    // ---- layer 2: 4096 x 18432 x 512, split-K=8 ----
    expand4_kernel<EMB, 0><<<M_BATCH, T, 0, stream>>>(Cpart, Cpart + MN, Phi, EMB);
    pack4_kernel<EMB><<<NPTS, T, 0, stream>>>(bw2, sw2, sc2, Wt, EMB);
    gemm_bt_256<<<dim3(2, 16, 8), 512, 0, stream>>>(Phi, Wt, Cpart, M_BATCH, NPTS, K12, K12 / 8);
    add8_kernel<<<(M_BATCH * NPTS / 4 + T - 1) / T, T, 0, stream>>>(
        Cpart, out, M_BATCH * NPTS / 4, M_BATCH * NPTS / 4);
}